// Round 5
// baseline (1130.633 us; speedup 1.0000x reference)
//
#include <hip/hip_runtime.h>
#include <hip/hip_fp16.h>
#include <stdint.h>

// DIEN (GRU -> DIN attention -> AUGRU) on MI355X.
// R5: recurrence rewritten on MFMA. 64 blocks x 512 thr (8 waves), 16 batches
// per block; wave w owns gate-cols j=w*16..w*16+15 via N-tiles {w,w+8,w+16}
// so (r,z,n) for one j are lane-local. Whh pre-packed to B-fragment layout
// (48 VGPR/wave). h in double-buffered XOR-swizzled LDS tile (conflict-free
// ds_read_b128 A-fragments). gi tile prefetched per step (issue-early/
// write-late). One barrier per step. attn / gi_gemm / prep / qdot from R4.

#define B_   1024
#define T_   200
#define H_   128
#define G3_  384
#define CH_  32
#define SCAN_BLOCKS 256

#define MT1  13
#define NT1  5
#define NT2  3
#define KS2N 3

#define WHHF_ELEMS (24 * 4 * 64 * 8)   // 49152 f16 per weight set

typedef _Float16 f16;
typedef _Float16 h2 __attribute__((ext_vector_type(2)));
typedef _Float16 h8 __attribute__((ext_vector_type(8)));
typedef float f32x4 __attribute__((ext_vector_type(4)));

union H8U { h8 v; h2 p[4]; };

#define USE_FDOT2 1

__device__ __forceinline__ float dot2a(h2 a, h2 b, float acc) {
#if USE_FDOT2
  return __builtin_amdgcn_fdot2(a, b, acc, false);
#else
  return fmaf((float)a[1], (float)b[1], fmaf((float)a[0], (float)b[0], acc));
#endif
}

__device__ __forceinline__ f32x4 mfma_h(h8 a, h8 b, f32x4 c) {
  return __builtin_amdgcn_mfma_f32_16x16x32_f16(a, b, c, 0, 0, 0);
}

__device__ __forceinline__ float sig_(float x)  { return 1.f / (1.f + __expf(-x)); }
__device__ __forceinline__ float tanh_(float x) { return 1.f - 2.f / (__expf(2.f * x) + 1.f); }

// ---------------------------------------------------------------- prep
__global__ void prep_kernel(
    const float* __restrict__ Wih_e, const float* __restrict__ Whh_e,
    const float* __restrict__ Wih_a, const float* __restrict__ Whh_a,
    const float* __restrict__ W1, const float* __restrict__ W2,
    const float* __restrict__ Wf,
    f16* __restrict__ wih_e_h, f16* __restrict__ whh_e_h,
    f16* __restrict__ wih_a_h, f16* __restrict__ whh_a_h,
    float* __restrict__ A1f, f16* __restrict__ Wfh,
    f16* __restrict__ wf1p, f16* __restrict__ wf2p,
    f16* __restrict__ whhf_e, f16* __restrict__ whhf_a)
{
  int i = blockIdx.x * 256 + threadIdx.x;
  const int NW = G3_ * H_;
  if (i < NW) { wih_e_h[i] = (f16)Wih_e[i]; return; }  i -= NW;
  if (i < NW) { whh_e_h[i] = (f16)Whh_e[i]; return; }  i -= NW;
  if (i < NW) { wih_a_h[i] = (f16)Wih_a[i]; return; }  i -= NW;
  if (i < NW) { whh_a_h[i] = (f16)Whh_a[i]; return; }  i -= NW;
  const int NB = 80 * 128;
  if (i < NB) { int o = i >> 7, jj = i & 127;
    A1f[i] = W1[o * 512 + jj] + W1[o * 512 + 256 + jj]; return; }  i -= NB;
  if (i < 40) { Wfh[i] = (f16)Wf[i]; return; }  i -= 40;
  if (i < NT1 * 8 * 64 * 8) {
    const int ii = i & 7, lane = (i >> 3) & 63, ks = (i >> 9) & 7, nt = i >> 12;
    const int kk = ks * 32 + ((lane >> 4) << 3) + ii;
    const int o = nt * 16 + (lane & 15);
    float v;
    if (kk < 128) v = W1[o * 512 + 128 + kk] - W1[o * 512 + 256 + kk];
    else          v = W1[o * 512 + 384 + (kk - 128)];
    wf1p[i] = (f16)v; return;
  }  i -= NT1 * 8 * 64 * 8;
  if (i < NT2 * KS2N * 64 * 8) {
    const int ii = i & 7, lane = (i >> 3) & 63, rem = i >> 9;
    const int ks = rem % KS2N, nt = rem / KS2N;
    const int k = ks * 32 + ((lane >> 4) << 3) + ii;
    const int o2 = nt * 16 + (lane & 15);
    wf2p[i] = (k < 80 && o2 < 40) ? (f16)W2[o2 * 80 + k] : (f16)0.f;
    return;
  }  i -= NT2 * KS2N * 64 * 8;
  // Whh B-fragment packs: idx = ((nt*4)+ks)*512 + lane*8 + ii,
  //   nt = g*8+cg: element = Whh[g*128 + cg*16 + (lane&15)][ks*32 + (lane>>4)*8 + ii]
  if (i < 2 * WHHF_ELEMS) {
    const int set = i / WHHF_ELEMS;
    const int r = i - set * WHHF_ELEMS;
    const int ii = r & 7, lane = (r >> 3) & 63, ks = (r >> 9) & 3, nt = r >> 11;
    const int row = (nt >> 3) * 128 + (nt & 7) * 16 + (lane & 15);
    const int col = ks * 32 + ((lane >> 4) << 3) + ii;
    const float* W = set ? Whh_a : Whh_e;
    (set ? whhf_a : whhf_e)[r] = (f16)W[row * H_ + col];
  }
}

// qdot[b][o] = b1[o] + sum_j A1[o][j] * q[b][j]
__global__ void qdot_kernel(const float* __restrict__ query, const float* __restrict__ A1f,
                            const float* __restrict__ b1, float* __restrict__ qdotp)
{
  const int b = blockIdx.x, o = threadIdx.x;
  if (o >= 80) return;
  float acc = b1[o];
  const float* qa = query + b * H_;
  const float* aa = A1f + o * H_;
  for (int jj = 0; jj < H_; ++jj) acc = fmaf(aa[jj], qa[jj], acc);
  qdotp[b * 80 + o] = acc;
}

// ---------------------------------------------------------------- gi GEMM (unchanged)
template <int XF32>
__global__ __launch_bounds__(256, 2) void gi_gemm_kernel(
    const float* __restrict__ xf32,
    const f16*  __restrict__ xh,
    const f16*  __restrict__ wih,
    const float* __restrict__ bih,
    f16* __restrict__ gi)
{
  __shared__ alignas(16) f16 xs[128 * H_];
  __shared__ alignas(16) f16 ws[192 * H_];
  const int tid = threadIdx.x;
  const int m0   = (blockIdx.x >> 1) * 128;
  const int half = blockIdx.x & 1;

  if (XF32) {
    for (int i = tid; i < 128 * 32; i += 256) {
      const int r = i >> 5, c = i & 31;
      float4 v = ((const float4*)(xf32 + (size_t)(m0 + r) * H_))[c];
      f16* dst = &xs[r * H_ + c * 4];
      dst[0] = (f16)v.x; dst[1] = (f16)v.y; dst[2] = (f16)v.z; dst[3] = (f16)v.w;
    }
  } else {
    const uint4* src = (const uint4*)(xh + (size_t)m0 * H_);
    for (int i = tid; i < 128 * 16; i += 256) ((uint4*)xs)[i] = src[i];
  }
  {
    const uint4* wsrc = (const uint4*)(wih + (size_t)half * 192 * H_);
    for (int i = tid; i < 192 * 16; i += 256) ((uint4*)ws)[i] = wsrc[i];
  }
  const int mg = tid >> 4;
  const int n0 = tid & 15;
  const int cb = half * 192 + n0 * 12;
  float bias[12];
#pragma unroll
  for (int ci = 0; ci < 12; ++ci) bias[ci] = bih[cb + ci];
  __syncthreads();

  float acc[8][12];
#pragma unroll
  for (int a = 0; a < 8; ++a)
#pragma unroll
    for (int c = 0; c < 12; ++c) acc[a][c] = 0.f;

  for (int kc = 0; kc < 16; ++kc) {
    const int kcp = (kc + n0) & 15;
    H8U xr[8], wr[12];
#pragma unroll
    for (int mi = 0; mi < 8; ++mi)
      xr[mi].v = *(const h8*)&xs[(mg * 8 + mi) * H_ + kcp * 8];
#pragma unroll
    for (int ci = 0; ci < 12; ++ci)
      wr[ci].v = *(const h8*)&ws[(n0 * 12 + ci) * H_ + kcp * 8];
#pragma unroll
    for (int mi = 0; mi < 8; ++mi)
#pragma unroll
      for (int ci = 0; ci < 12; ++ci)
#pragma unroll
        for (int q = 0; q < 4; ++q)
          acc[mi][ci] = dot2a(xr[mi].p[q], wr[ci].p[q], acc[mi][ci]);
  }

#pragma unroll
  for (int mi = 0; mi < 8; ++mi) {
    const size_t row = (size_t)(m0 + mg * 8 + mi);
    f16 o12[12];
#pragma unroll
    for (int ci = 0; ci < 12; ++ci) o12[ci] = (f16)(acc[mi][ci] + bias[ci]);
    f16* dst = gi + row * G3_ + cb;
#pragma unroll
    for (int s = 0; s < 3; ++s)
      ((uint2*)dst)[s] = *(const uint2*)&o12[s * 4];
  }
}

// ---------------------------------------------------------------- recurrence (MFMA)
// 64 blocks x 512 thr (8 waves). Block: batches bg..bg+15. Wave w: gate cols
// j = w*16+(lane&15); N-tiles {w, w+8, w+16} -> r/z/n lane-local.
template <int AUGRU>
__global__ __launch_bounds__(512, 2) void srec_mfma_kernel(
    const f16*  __restrict__ gi_all,   // [B*T,384]
    const int*  __restrict__ lens,
    const f16*  __restrict__ whhf,     // [24][4][64][8] B-fragments
    const float* __restrict__ bhh,
    const float* __restrict__ scores,  // AUGRU only
    f16*  __restrict__ interests_out,  // GRU only
    float* __restrict__ hout)          // AUGRU only
{
  __shared__ alignas(16) f16 gi_lds[2][16 * G3_];   // 24576 B
  __shared__ alignas(16) f16 h_lds[2][16 * H_];     //  8192 B (swizzled 16B slots)
  __shared__ float scr_lds[2][16];

  const int tid = threadIdx.x;
  const int lane = tid & 63, wid = tid >> 6;
  const int bg = blockIdx.x * 16;
  const int row16 = lane & 15;        // A-frag row / C-frag col
  const int kb = lane >> 4;           // 0..3
  const int jcol = wid * 16 + row16;  // gate column 0..127
  const int brow0 = kb * 4;           // C/D batch rows brow0..brow0+3

  // weights -> 12 h8 (48 VGPRs)
  h8 wb[3][4];
#pragma unroll
  for (int g = 0; g < 3; ++g)
#pragma unroll
    for (int ks = 0; ks < 4; ++ks)
      wb[g][ks] = *(const h8*)(whhf + (size_t)(((g * 8 + wid) * 4 + ks) * 64 + lane) * 8);

  const float bh0 = bhh[jcol], bh1 = bhh[jcol + 128], bh2 = bhh[jcol + 256];
  int len4[4];
#pragma unroll
  for (int r = 0; r < 4; ++r) len4[r] = lens[bg + brow0 + r];
  float hk[4] = {0.f, 0.f, 0.f, 0.f};

  // h_lds[0] = 0
  for (int i = tid; i < 16 * H_ / 2; i += 512) ((uint*)h_lds[0])[i] = 0u;
  // prologue: stage gi/scores for t=0 into buf 0
  {
    const int idx0 = tid;
    const int row = idx0 / 48, c = idx0 - row * 48;
    ((uint4*)gi_lds[0])[idx0] =
        ((const uint4*)(gi_all + ((size_t)(bg + row) * T_) * G3_))[c];
    if (tid < 256) {
      const int idx1 = tid + 512;
      const int row1 = idx1 / 48, c1 = idx1 - row1 * 48;
      ((uint4*)gi_lds[0])[idx1] =
          ((const uint4*)(gi_all + ((size_t)(bg + row1) * T_) * G3_))[c1];
    }
    if (AUGRU && tid < 16) scr_lds[0][tid] = scores[(size_t)(bg + tid) * T_];
  }
  __syncthreads();

  int p = 0, q = 0;
  for (int t = 0; t < T_; ++t) {
    // ---- issue prefetch (t+1) ----
    const int tp = (t + 1 < T_) ? (t + 1) : (T_ - 1);
    uint4 g0, g1;
    float s0 = 0.f;
    {
      const int row = tid / 48, c = tid - row * 48;
      g0 = ((const uint4*)(gi_all + ((size_t)(bg + row) * T_ + tp) * G3_))[c];
      if (tid < 256) {
        const int idx1 = tid + 512;
        const int row1 = idx1 / 48, c1 = idx1 - row1 * 48;
        g1 = ((const uint4*)(gi_all + ((size_t)(bg + row1) * T_ + tp) * G3_))[c1];
      }
      if (AUGRU && tid < 16) s0 = scores[(size_t)(bg + tid) * T_ + tp];
    }

    // ---- A-fragments from swizzled h_lds[p] ----
    h8 ha[4];
#pragma unroll
    for (int ks = 0; ks < 4; ++ks) {
      const int slot = (ks * 4 + kb) ^ row16;          // 16B-slot swizzle
      ha[ks] = *(const h8*)&h_lds[p][row16 * H_ + (slot & 15) * 8];
    }

    // ---- MFMA: gh + bhh ----
    f32x4 a0 = {bh0, bh0, bh0, bh0};
    f32x4 a1 = {bh1, bh1, bh1, bh1};
    f32x4 a2 = {bh2, bh2, bh2, bh2};
#pragma unroll
    for (int ks = 0; ks < 4; ++ks) {
      a0 = mfma_h(ha[ks], wb[0][ks], a0);
      a1 = mfma_h(ha[ks], wb[1][ks], a1);
      a2 = mfma_h(ha[ks], wb[2][ks], a2);
    }

    // ---- gates (lane-local) ----
    const f16* gl = gi_lds[q];
#pragma unroll
    for (int r = 0; r < 4; ++r) {
      const int row = brow0 + r;
      const float gir = (float)gl[row * G3_ + jcol];
      const float giz = (float)gl[row * G3_ + 128 + jcol];
      const float gin = (float)gl[row * G3_ + 256 + jcol];
      const float rr = sig_(gir + a0[r]);
      const float nn = tanh_(gin + rr * a2[r]);
      float hnew;
      if (AUGRU) {
        const float u = sig_(giz + a1[r]) * scr_lds[q][row];
        hnew = (1.f - u) * hk[r] + u * nn;     // AUGRU: u gates NEW state
      } else {
        const float z = sig_(giz + a1[r]);
        hnew = (1.f - z) * nn + z * hk[r];     // torch GRU convention
      }
      if (t < len4[r]) hk[r] = hnew;
      const int slot = (jcol >> 3) ^ row;
      h_lds[p ^ 1][row * H_ + (slot & 15) * 8 + (jcol & 7)] = (f16)hk[r];
      if (!AUGRU)
        interests_out[((size_t)(bg + row) * T_ + t) * H_ + jcol] = (f16)hk[r];
    }

    // ---- write prefetched gi/scores ----
    {
      ((uint4*)gi_lds[q ^ 1])[tid] = g0;
      if (tid < 256) ((uint4*)gi_lds[q ^ 1])[tid + 512] = g1;
      if (AUGRU && tid < 16) scr_lds[q ^ 1][tid] = s0;
    }
    __syncthreads();
    p ^= 1; q ^= 1;
  }

  if (AUGRU) {
#pragma unroll
    for (int r = 0; r < 4; ++r)
      hout[(size_t)(bg + brow0 + r) * H_ + jcol] = hk[r];
  }
}

// ================================================================ fallback monolithic scan
template <int AUGRU>
__global__ __launch_bounds__(256, 1) void scan_kernel(
    const float* __restrict__ keys_f32,
    const f16*  __restrict__ x_f16,
    const int*  __restrict__ lens,
    const f16*  __restrict__ wih,
    const f16*  __restrict__ whh,
    const float* __restrict__ bih,
    const float* __restrict__ bhh,
    const float* __restrict__ scores,
    f16*  __restrict__ interests_out,
    float* __restrict__ hout,
    f16*  __restrict__ gi_all)
{
  __shared__ alignas(16) f16 wlds[G3_ * H_];
  __shared__ alignas(16) f16 xlds[CH_ * 4 * H_];
  __shared__ alignas(16) f16 hbuf[2][4 * H_];
  __shared__ float bihs[G3_];

  const int tid = threadIdx.x;
  const int b0 = blockIdx.x * 4;
  f16* gi_ws = gi_all + (size_t)blockIdx.x * (CH_ * 4 * G3_);

  for (int i = tid; i < G3_; i += 256) bihs[i] = bih[i];
  for (int i = tid; i < 2 * 4 * H_; i += 256) ((f16*)hbuf)[i] = (f16)0.f;
  {
    const uint4* src = (const uint4*)wih;
    uint4* dst = (uint4*)wlds;
    for (int idx = tid; idx < G3_ * H_ / 8; idx += 256) dst[idx] = src[idx];
  }

  const int j  = tid & 127;
  const int bp = tid >> 7;
  const int len0 = lens[b0 + bp];
  const int len1 = lens[b0 + bp + 2];
  const float bhr = bhh[j], bhz = bhh[j + 128], bhn = bhh[j + 256];
  const int mg = tid >> 4;
  const int n0 = tid & 15;

  H8U wr_r[16], wr_z[16], wr_n[16];
#pragma unroll
  for (int c = 0; c < 16; ++c) {
    wr_r[c].v = *(const h8*)(whh + (size_t)(j)       * H_ + c * 8);
    wr_z[c].v = *(const h8*)(whh + (size_t)(j + 128) * H_ + c * 8);
    wr_n[c].v = *(const h8*)(whh + (size_t)(j + 256) * H_ + c * 8);
  }

  float hreg[2] = {0.f, 0.f};
  int p = 0;
  __syncthreads();

  for (int t0 = 0; t0 < T_; t0 += CH_) {
    const int S = (T_ - t0 < CH_) ? (T_ - t0) : CH_;
    if (AUGRU) {
      const int NV = S * 4 * 16;
      for (int idx = tid; idx < NV; idx += 256) {
        int b = idx / (S * 16);
        int rem = idx - b * (S * 16);
        int tp = rem >> 4, c = rem & 15;
        const uint4* src = (const uint4*)(x_f16 + ((size_t)(b0 + b) * T_ + (t0 + tp)) * H_);
        ((uint4*)xlds)[(tp * 4 + b) * 16 + c] = src[c];
      }
    } else {
      const int NV = S * 4 * 32;
      for (int idx = tid; idx < NV; idx += 256) {
        int b = idx / (S * 32);
        int rem = idx - b * (S * 32);
        int tp = rem >> 5, c = rem & 31;
        const float4* src = (const float4*)(keys_f32 + ((size_t)(b0 + b) * T_ + (t0 + tp)) * H_);
        float4 v = src[c];
        f16* dst = &xlds[(tp * 4 + b) * H_ + c * 4];
        dst[0] = (f16)v.x; dst[1] = (f16)v.y; dst[2] = (f16)v.z; dst[3] = (f16)v.w;
      }
    }
    __syncthreads();
    for (int ngrp = 0; ngrp < 3; ++ngrp) {
      float acc[8][8];
#pragma unroll
      for (int a = 0; a < 8; ++a)
#pragma unroll
        for (int c = 0; c < 8; ++c) acc[a][c] = 0.f;
      for (int kc = 0; kc < 16; ++kc) {
        const int kcp = (kc + n0) & 15;
        H8U xr[8], wr[8];
#pragma unroll
        for (int mi = 0; mi < 8; ++mi)
          xr[mi].v = *(const h8*)&xlds[(mg * 8 + mi) * H_ + kcp * 8];
#pragma unroll
        for (int ni = 0; ni < 8; ++ni)
          wr[ni].v = *(const h8*)&wlds[(n0 * 24 + ngrp * 8 + ni) * H_ + kcp * 8];
#pragma unroll
        for (int mi = 0; mi < 8; ++mi)
#pragma unroll
          for (int ni = 0; ni < 8; ++ni)
#pragma unroll
            for (int q = 0; q < 4; ++q)
              acc[mi][ni] = dot2a(xr[mi].p[q], wr[ni].p[q], acc[mi][ni]);
      }
#pragma unroll
      for (int mi = 0; mi < 8; ++mi) {
        const int pr = mg * 8 + mi;
        if (pr < S * 4) {
          H8U o8;
#pragma unroll
          for (int ni = 0; ni < 8; ++ni) {
            const int g = n0 * 24 + ngrp * 8 + ni;
            o8.p[ni >> 1][ni & 1] = (f16)(acc[mi][ni] + bihs[g]);
          }
          *(h8*)&gi_ws[(size_t)pr * G3_ + n0 * 24 + ngrp * 8] = o8.v;
        }
      }
    }
    __syncthreads();
    for (int tp = 0; tp < S; ++tp) {
      const int t = t0 + tp;
      float hr[2] = {0.f, 0.f}, hz[2] = {0.f, 0.f}, hn[2] = {0.f, 0.f};
#pragma unroll
      for (int kc = 0; kc < 16; ++kc) {
        H8U hv0, hv1;
        hv0.v = *(const h8*)&hbuf[p][(bp)     * H_ + kc * 8];
        hv1.v = *(const h8*)&hbuf[p][(bp + 2) * H_ + kc * 8];
#pragma unroll
        for (int q = 0; q < 4; ++q) {
          hr[0] = dot2a(wr_r[kc].p[q], hv0.p[q], hr[0]);
          hz[0] = dot2a(wr_z[kc].p[q], hv0.p[q], hz[0]);
          hn[0] = dot2a(wr_n[kc].p[q], hv0.p[q], hn[0]);
          hr[1] = dot2a(wr_r[kc].p[q], hv1.p[q], hr[1]);
          hz[1] = dot2a(wr_z[kc].p[q], hv1.p[q], hz[1]);
          hn[1] = dot2a(wr_n[kc].p[q], hv1.p[q], hn[1]);
        }
      }
#pragma unroll
      for (int bb = 0; bb < 2; ++bb) {
        const int b = bp + bb * 2;
        const int gb = b0 + b;
        const f16* gi = &gi_ws[(size_t)(tp * 4 + b) * G3_];
        const float gr  = (float)gi[j]       + hr[bb] + bhr;
        const float gz  = (float)gi[j + 128] + hz[bb] + bhz;
        const float gin = (float)gi[j + 256];
        const float r = sig_(gr);
        const float nn = tanh_(gin + r * (hn[bb] + bhn));
        float hnew;
        if (AUGRU) {
          const float a = scores[(size_t)gb * T_ + t];
          const float u = sig_(gz) * a;
          hnew = (1.f - u) * hreg[bb] + u * nn;
        } else {
          const float z = sig_(gz);
          hnew = (1.f - z) * nn + z * hreg[bb];
        }
        const int mylen = bb ? len1 : len0;
        if (t < mylen) hreg[bb] = hnew;
        hbuf[p ^ 1][b * H_ + j] = (f16)hreg[bb];
        if (!AUGRU) interests_out[((size_t)gb * T_ + t) * H_ + j] = (f16)hreg[bb];
      }
      __syncthreads();
      p ^= 1;
    }
  }
  if (AUGRU) {
    hout[(size_t)(b0 + bp) * H_ + j]     = hreg[0];
    hout[(size_t)(b0 + bp + 2) * H_ + j] = hreg[1];
  }
}

// ---------------------------------------------------------------- attention (MFMA, softmax fused)
__global__ __launch_bounds__(512, 1) void attn_kernel(
    const float* __restrict__ query,
    const f16* __restrict__ interests,
    const f16* __restrict__ wf1g,
    const f16* __restrict__ wf2g,
    const f16* __restrict__ wfg,
    const float* __restrict__ qdotp,
    const float* __restrict__ b2,
    const float* __restrict__ bfp,
    const int* __restrict__ lens,
    float* __restrict__ scores)
{
  __shared__ alignas(16) f16 wf1[NT1 * 8 * 64 * 8];
  __shared__ alignas(16) f16 wf2[NT2 * KS2N * 64 * 8];
  __shared__ alignas(16) f16 uni[29952];
  __shared__ alignas(16) f16 qh[128];
  __shared__ alignas(16) f16 wfv[40];
  __shared__ float qd[80];
  __shared__ float b2s[40];
  __shared__ float red[256];

  f16* ktf = uni;
  f16* h1f = uni;
  f16* h2s = uni + MT1 * KS2N * 64 * 8;

  const int tid = threadIdx.x;
  const int b = blockIdx.x;
  const int lane = tid & 63, wid = tid >> 6;
  const int row = lane & 15, kb = lane >> 4;

  for (int idx = tid; idx < NT1 * 8 * 64; idx += 512)
    ((uint4*)wf1)[idx] = ((const uint4*)wf1g)[idx];
  for (int idx = tid; idx < NT2 * KS2N * 64; idx += 512)
    ((uint4*)wf2)[idx] = ((const uint4*)wf2g)[idx];
  for (int idx = tid; idx < MT1 * 4 * 64; idx += 512) {
    const int l = idx & 63, ks = (idx >> 6) & 3, mt = idx >> 8;
    const int t = mt * 16 + (l & 15);
    uint4 v = make_uint4(0u, 0u, 0u, 0u);
    if (t < T_)
      v = *(const uint4*)(interests + ((size_t)b * T_ + t) * H_ + ks * 32 + ((l >> 4) << 3));
    ((uint4*)ktf)[idx] = v;
  }
  if (tid < 32) {
    float4 qv = ((const float4*)(query + (size_t)b * H_))[tid];
    f16* d = &qh[tid * 4];
    d[0] = (f16)qv.x; d[1] = (f16)qv.y; d[2] = (f16)qv.z; d[3] = (f16)qv.w;
  }
  if (tid < 80) qd[tid] = qdotp[(size_t)b * 80 + tid];
  if (tid >= 128 && tid < 168) wfv[tid - 128] = wfg[tid - 128];
  if (tid >= 192 && tid < 232) b2s[tid - 192] = b2[tid - 192];
  __syncthreads();

  const int nmt = (wid + 8 < MT1) ? 2 : 1;
  const int mts[2] = { wid, wid + 8 };

  h8 qf[4];
#pragma unroll
  for (int h = 0; h < 4; ++h) qf[h] = *(const h8*)&qh[h * 32 + kb * 8];

  h8 afr[2][4], qa[2][4];
#pragma unroll
  for (int m = 0; m < 2; ++m) if (m < nmt) {
#pragma unroll
    for (int ks = 0; ks < 4; ++ks) {
      afr[m][ks] = *(const h8*)&ktf[((mts[m] * 4 + ks) * 64 + lane) * 8];
      qa[m][ks] = afr[m][ks] * qf[ks];
    }
  }
  __syncthreads();

  f32x4 acc[2][NT1];
#pragma unroll
  for (int m = 0; m < 2; ++m)
#pragma unroll
    for (int n = 0; n < NT1; ++n) acc[m][n] = (f32x4){0.f, 0.f, 0.f, 0.f};

  for (int nt = 0; nt < NT1; ++nt) {
#pragma unroll
    for (int ks = 0; ks < 8; ++ks) {
      const h8 bfr = *(const h8*)&wf1[((nt * 8 + ks) * 64 + lane) * 8];
#pragma unroll
      for (int m = 0; m < 2; ++m) if (m < nmt)
        acc[m][nt] = mfma_h(ks < 4 ? afr[m][ks] : qa[m][ks - 4], bfr, acc[m][nt]);
    }
  }

#pragma unroll
  for (int m = 0; m < 2; ++m) if (m < nmt) {
    const int mt = mts[m];
#pragma unroll
    for (int nt = 0; nt < NT1; ++nt) {
      const int o = nt * 16 + row;
      const float qdo = qd[o];
#pragma unroll
      for (int r = 0; r < 4; ++r) {
        const float val = sig_(acc[m][nt][r] + qdo);
        const int lr = kb * 4 + r;
        const int ks2 = o >> 5, kb2 = (o >> 3) & 3, i2 = o & 7;
        h1f[((mt * KS2N + ks2) * 64 + (lr | (kb2 << 4))) * 8 + i2] = (f16)val;
      }
    }
  }
  for (int idx = tid; idx < MT1 * 32 * 8; idx += 512) {
    const int mt = idx >> 8, rr = idx & 255;
    h1f[((mt * KS2N + 2) * 64 + 32 + (rr >> 3)) * 8 + (rr & 7)] = (f16)0.f;
  }
  __syncthreads();

  h8 a2[2][KS2N];
#pragma unroll
  for (int m = 0; m < 2; ++m) if (m < nmt)
#pragma unroll
    for (int ks = 0; ks < KS2N; ++ks)
      a2[m][ks] = *(const h8*)&h1f[((mts[m] * KS2N + ks) * 64 + lane) * 8];

  f32x4 acc2[2][NT2];
#pragma unroll
  for (int m = 0; m < 2; ++m)
#pragma unroll
    for (int n = 0; n < NT2; ++n) acc2[m][n] = (f32x4){0.f, 0.f, 0.f, 0.f};

#pragma unroll
  for (int nt = 0; nt < NT2; ++nt)
#pragma unroll
    for (int ks = 0; ks < KS2N; ++ks) {
      const h8 bfr = *(const h8*)&wf2[((nt * KS2N + ks) * 64 + lane) * 8];
#pragma unroll
      for (int m = 0; m < 2; ++m) if (m < nmt)
        acc2[m][nt] = mfma_h(a2[m][ks], bfr, acc2[m][nt]);
    }

#pragma unroll
  for (int m = 0; m < 2; ++m) if (m < nmt) {
#pragma unroll
    for (int nt = 0; nt < NT2; ++nt) {
      const int o2 = nt * 16 + row;
      if (o2 < 40) {
        const float bo = b2s[o2];
#pragma unroll
        for (int r = 0; r < 4; ++r) {
          const int t = mts[m] * 16 + kb * 4 + r;
          h2s[t * 48 + o2] = (f16)sig_(acc2[m][nt][r] + bo);
        }
      }
    }
  }
  __syncthreads();

  float logit = 0.f;
  if (tid < T_) {
    float a = 0.f;
#pragma unroll
    for (int c = 0; c < 5; ++c) {
      H8U wv, hv;
      wv.v = *(const h8*)&wfv[c * 8];
      hv.v = *(const h8*)&h2s[tid * 48 + c * 8];
#pragma unroll
      for (int q = 0; q < 4; ++q) a = dot2a(wv.p[q], hv.p[q], a);
    }
    logit = (a + bfp[0]) * 0.088388347648318447f;
  }
  const int len = lens[b];
  if (tid < 256) red[tid] = (tid < T_ && tid < len) ? logit : -1e30f;
  __syncthreads();
  for (int s = 128; s > 0; s >>= 1) {
    if (tid < s) red[tid] = fmaxf(red[tid], red[tid + s]);
    __syncthreads();
  }
  const float mx = red[0];
  __syncthreads();
  const float e = (tid < T_ && tid < len) ? __expf(logit - mx) : 0.f;
  if (tid < 256) red[tid] = e;
  __syncthreads();
  for (int s = 128; s > 0; s >>= 1) {
    if (tid < s) red[tid] += red[tid + s];
    __syncthreads();
  }
  if (tid < T_) scores[(size_t)b * T_ + tid] = e * (1.f / red[0]);
}

// ---------------------------------------------------------------- launcher
extern "C" void kernel_launch(void* const* d_in, const int* in_sizes, int n_in,
                              void* d_out, int out_size, void* d_ws, size_t ws_size,
                              hipStream_t stream)
{
  (void)in_sizes; (void)n_in; (void)out_size;
  const float* query = (const float*)d_in[0];
  const float* keys  = (const float*)d_in[1];
  const int*   lens  = (const int*)d_in[2];
  const float* Wih_e = (const float*)d_in[3];
  const float* Whh_e = (const float*)d_in[4];
  const float* bih_e = (const float*)d_in[5];
  const float* bhh_e = (const float*)d_in[6];
  const float* Wih_a = (const float*)d_in[7];
  const float* Whh_a = (const float*)d_in[8];
  const float* bih_a = (const float*)d_in[9];
  const float* bhh_a = (const float*)d_in[10];
  const float* W1 = (const float*)d_in[11];
  const float* b1 = (const float*)d_in[12];
  const float* W2 = (const float*)d_in[13];
  const float* b2 = (const float*)d_in[14];
  const float* Wf = (const float*)d_in[15];
  const float* bf = (const float*)d_in[16];

  char* w = (char*)d_ws;
  size_t off = 0;
  auto take = [&](size_t bytes) { char* p = w + off; off += (bytes + 255) & ~(size_t)255; return p; };

  f16*   interests = (f16*)take((size_t)B_ * T_ * H_ * 2);
  float* scores    = (float*)take((size_t)B_ * T_ * 4);
  f16*   wih_e_h = (f16*)take(G3_ * H_ * 2);
  f16*   whh_e_h = (f16*)take(G3_ * H_ * 2);
  f16*   wih_a_h = (f16*)take(G3_ * H_ * 2);
  f16*   whh_a_h = (f16*)take(G3_ * H_ * 2);
  float* A1f = (float*)take(80 * 128 * 4);
  f16*   Wfh = (f16*)take(64 * 2);
  f16*   wf1p = (f16*)take(NT1 * 8 * 64 * 8 * 2);
  f16*   wf2p = (f16*)take(NT2 * KS2N * 64 * 8 * 2);
  f16*   whhf_e = (f16*)take(WHHF_ELEMS * 2);
  f16*   whhf_a = (f16*)take(WHHF_ELEMS * 2);
  float* qdotp = (float*)take((size_t)B_ * 80 * 4);

  const size_t small_off = off;
  f16* gi_big = (f16*)take((size_t)B_ * T_ * G3_ * 2);
  const size_t need_big = off;
  const bool big = (ws_size >= need_big);
  off = small_off;
  f16* gi_ws = (f16*)take((size_t)SCAN_BLOCKS * CH_ * 4 * G3_ * 2);

  const int prep_tasks = 4 * G3_ * H_ + 80 * 128 + 40
                       + NT1 * 8 * 64 * 8 + NT2 * KS2N * 64 * 8
                       + 2 * WHHF_ELEMS;
  prep_kernel<<<(prep_tasks + 255) / 256, 256, 0, stream>>>(
      Wih_e, Whh_e, Wih_a, Whh_a, W1, W2, Wf,
      wih_e_h, whh_e_h, wih_a_h, whh_a_h, A1f, Wfh, wf1p, wf2p, whhf_e, whhf_a);
  qdot_kernel<<<B_, 128, 0, stream>>>(query, A1f, b1, qdotp);

  if (big) {
    gi_gemm_kernel<1><<<(B_ * T_ / 128) * 2, 256, 0, stream>>>(
        keys, (const f16*)nullptr, wih_e_h, bih_e, gi_big);
    srec_mfma_kernel<0><<<B_ / 16, 512, 0, stream>>>(
        gi_big, lens, whhf_e, bhh_e, (const float*)nullptr, interests, (float*)nullptr);
    attn_kernel<<<B_, 512, 0, stream>>>(
        query, interests, wf1p, wf2p, Wfh, qdotp, b2, bf, lens, scores);
    gi_gemm_kernel<0><<<(B_ * T_ / 128) * 2, 256, 0, stream>>>(
        (const float*)nullptr, interests, wih_a_h, bih_a, gi_big);
    srec_mfma_kernel<1><<<B_ / 16, 512, 0, stream>>>(
        gi_big, lens, whhf_a, bhh_a, scores, (f16*)nullptr, (float*)d_out);
  } else {
    scan_kernel<0><<<SCAN_BLOCKS, 256, 0, stream>>>(
        keys, (const f16*)nullptr, lens, wih_e_h, whh_e_h, bih_e, bhh_e,
        (const float*)nullptr, interests, (float*)nullptr, gi_ws);
    attn_kernel<<<B_, 512, 0, stream>>>(
        query, interests, wf1p, wf2p, Wfh, qdotp, b2, bf, lens, scores);
    scan_kernel<1><<<SCAN_BLOCKS, 256, 0, stream>>>(
        (const float*)nullptr, interests, lens, wih_a_h, whh_a_h, bih_a, bhh_a,
        scores, (f16*)nullptr, (float*)d_out, gi_ws);
  }
}

// Round 6
// 824.707 us; speedup vs baseline: 1.3710x; 1.3710x over previous
//
#include <hip/hip_runtime.h>
#include <hip/hip_fp16.h>
#include <stdint.h>

// DIEN (GRU -> DIN attention -> AUGRU) on MI355X.
// R6: two fixes.
//  (1) srec: gi/scores now per-thread REGISTER prefetch (no LDS, no race),
//      raw s_barrier + lgkmcnt(0) fence (no vmcnt drain -> prefetch loads
//      stay in flight across the barrier). 2x-unrolled register dbuf.
//  (2) gi_gemm rewritten on MFMA: Wih pre-packed to B-fragments (96 VGPR/wave),
//      X staged to LDS A-fragment layout, wave tile 4 M-tiles x 6 N-tiles.
// attn (MFMA+fused softmax), prep, qdot unchanged from R4/R5.

#define B_   1024
#define T_   200
#define H_   128
#define G3_  384
#define CH_  32
#define SCAN_BLOCKS 256

#define MT1  13
#define NT1  5
#define NT2  3
#define KS2N 3

#define WHHF_ELEMS (24 * 4 * 64 * 8)   // 49152 f16 per [384][128] frag pack

typedef _Float16 f16;
typedef _Float16 h2 __attribute__((ext_vector_type(2)));
typedef _Float16 h8 __attribute__((ext_vector_type(8)));
typedef float f32x4 __attribute__((ext_vector_type(4)));

union H8U { h8 v; h2 p[4]; };

#define USE_FDOT2 1

__device__ __forceinline__ float dot2a(h2 a, h2 b, float acc) {
#if USE_FDOT2
  return __builtin_amdgcn_fdot2(a, b, acc, false);
#else
  return fmaf((float)a[1], (float)b[1], fmaf((float)a[0], (float)b[0], acc));
#endif
}

__device__ __forceinline__ f32x4 mfma_h(h8 a, h8 b, f32x4 c) {
  return __builtin_amdgcn_mfma_f32_16x16x32_f16(a, b, c, 0, 0, 0);
}

__device__ __forceinline__ float sig_(float x)  { return 1.f / (1.f + __expf(-x)); }
__device__ __forceinline__ float tanh_(float x) { return 1.f - 2.f / (__expf(2.f * x) + 1.f); }

// ---------------------------------------------------------------- prep
__global__ void prep_kernel(
    const float* __restrict__ Wih_e, const float* __restrict__ Whh_e,
    const float* __restrict__ Wih_a, const float* __restrict__ Whh_a,
    const float* __restrict__ W1, const float* __restrict__ W2,
    const float* __restrict__ Wf,
    f16* __restrict__ wih_e_h, f16* __restrict__ whh_e_h,
    f16* __restrict__ wih_a_h, f16* __restrict__ whh_a_h,
    float* __restrict__ A1f, f16* __restrict__ Wfh,
    f16* __restrict__ wf1p, f16* __restrict__ wf2p,
    f16* __restrict__ whhf_e, f16* __restrict__ whhf_a,
    f16* __restrict__ wihf_e, f16* __restrict__ wihf_a)
{
  int i = blockIdx.x * 256 + threadIdx.x;
  const int NW = G3_ * H_;
  if (i < NW) { wih_e_h[i] = (f16)Wih_e[i]; return; }  i -= NW;
  if (i < NW) { whh_e_h[i] = (f16)Whh_e[i]; return; }  i -= NW;
  if (i < NW) { wih_a_h[i] = (f16)Wih_a[i]; return; }  i -= NW;
  if (i < NW) { whh_a_h[i] = (f16)Whh_a[i]; return; }  i -= NW;
  const int NB = 80 * 128;
  if (i < NB) { int o = i >> 7, jj = i & 127;
    A1f[i] = W1[o * 512 + jj] + W1[o * 512 + 256 + jj]; return; }  i -= NB;
  if (i < 40) { Wfh[i] = (f16)Wf[i]; return; }  i -= 40;
  if (i < NT1 * 8 * 64 * 8) {
    const int ii = i & 7, lane = (i >> 3) & 63, ks = (i >> 9) & 7, nt = i >> 12;
    const int kk = ks * 32 + ((lane >> 4) << 3) + ii;
    const int o = nt * 16 + (lane & 15);
    float v;
    if (kk < 128) v = W1[o * 512 + 128 + kk] - W1[o * 512 + 256 + kk];
    else          v = W1[o * 512 + 384 + (kk - 128)];
    wf1p[i] = (f16)v; return;
  }  i -= NT1 * 8 * 64 * 8;
  if (i < NT2 * KS2N * 64 * 8) {
    const int ii = i & 7, lane = (i >> 3) & 63, rem = i >> 9;
    const int ks = rem % KS2N, nt = rem / KS2N;
    const int k = ks * 32 + ((lane >> 4) << 3) + ii;
    const int o2 = nt * 16 + (lane & 15);
    wf2p[i] = (k < 80 && o2 < 40) ? (f16)W2[o2 * 80 + k] : (f16)0.f;
    return;
  }  i -= NT2 * KS2N * 64 * 8;
  // generic [384][128] -> B-fragment packs: value = W[nt*16+(lane&15)][ks*32+(lane>>4)*8+ii]
  if (i < 4 * WHHF_ELEMS) {
    const int set = i / WHHF_ELEMS;
    const int r = i - set * WHHF_ELEMS;
    const int ii = r & 7, lane = (r >> 3) & 63, ks = (r >> 9) & 3, nt = r >> 11;
    const int row = nt * 16 + (lane & 15);
    const int col = ks * 32 + ((lane >> 4) << 3) + ii;
    const float* W = (set == 0) ? Whh_e : (set == 1) ? Whh_a : (set == 2) ? Wih_e : Wih_a;
    f16* D = (set == 0) ? whhf_e : (set == 1) ? whhf_a : (set == 2) ? wihf_e : wihf_a;
    D[r] = (f16)W[row * H_ + col];
  }
}

// qdot[b][o] = b1[o] + sum_j A1[o][j] * q[b][j]
__global__ void qdot_kernel(const float* __restrict__ query, const float* __restrict__ A1f,
                            const float* __restrict__ b1, float* __restrict__ qdotp)
{
  const int b = blockIdx.x, o = threadIdx.x;
  if (o >= 80) return;
  float acc = b1[o];
  const float* qa = query + b * H_;
  const float* aa = A1f + o * H_;
  for (int jj = 0; jj < H_; ++jj) acc = fmaf(aa[jj], qa[jj], acc);
  qdotp[b * 80 + o] = acc;
}

// ---------------------------------------------------------------- gi GEMM (MFMA)
// C[M=204800][384] = X[M][128] . Wih^T, +bih. Block: 128 rows, full N=384.
// 8 waves as (wr 0..1, wc 0..3): wave tile = 4 M-tiles x 6 N-tiles.
// Wih B-fragments in VGPRs (24 x h8), X staged in LDS A-frag layout.
template <int XF32>
__global__ __launch_bounds__(512, 1) void gi_gemm_mfma_kernel(
    const float* __restrict__ xf32,   // XF32: [M,128] f32
    const f16*  __restrict__ xh,      // else: [M,128] f16
    const f16*  __restrict__ wihf,    // [24][4][64][8] B-fragments
    const float* __restrict__ bih,
    f16* __restrict__ gi)             // [M,384]
{
  __shared__ alignas(16) f16 xa[8 * 4 * 64 * 8];   // 32KB A-fragments
  const int tid = threadIdx.x;
  const int lane = tid & 63, wid = tid >> 6;
  const int m0 = blockIdx.x * 128;
  const int row16 = lane & 15, kb = lane >> 4;
  const int wr = wid >> 2, wc = wid & 3;

  // B fragments + bias (from global; Wih pack is L2-hot)
  h8 wb[6][4];
#pragma unroll
  for (int n = 0; n < 6; ++n)
#pragma unroll
    for (int ks = 0; ks < 4; ++ks)
      wb[n][ks] = *(const h8*)(wihf + (size_t)(((wc * 6 + n) * 4 + ks) * 64 + lane) * 8);
  float bias[6];
#pragma unroll
  for (int n = 0; n < 6; ++n) bias[n] = bih[(wc * 6 + n) * 16 + row16];

  // stage X -> A-frag layout: slot (mt,ks,lane): 16B from row m0+mt*16+(lane&15),
  // cols ks*32+(lane>>4)*8 .. +7
  for (int s = tid; s < 2048; s += 512) {
    const int l = s & 63, ks = (s >> 6) & 3, mt = s >> 8;
    const int row = m0 + mt * 16 + (l & 15);
    const int col = ks * 32 + ((l >> 4) << 3);
    if (XF32) {
      const float* src = xf32 + (size_t)row * H_ + col;
      float4 v0 = *(const float4*)(src);
      float4 v1 = *(const float4*)(src + 4);
      f16 t8[8] = {(f16)v0.x, (f16)v0.y, (f16)v0.z, (f16)v0.w,
                   (f16)v1.x, (f16)v1.y, (f16)v1.z, (f16)v1.w};
      *(uint4*)&xa[s * 8] = *(const uint4*)t8;
    } else {
      *(uint4*)&xa[s * 8] = *(const uint4*)(xh + (size_t)row * H_ + col);
    }
  }
  __syncthreads();

  f32x4 acc[4][6];
#pragma unroll
  for (int m = 0; m < 4; ++m)
#pragma unroll
    for (int n = 0; n < 6; ++n) acc[m][n] = (f32x4){0.f, 0.f, 0.f, 0.f};

#pragma unroll
  for (int m = 0; m < 4; ++m) {
    const int mt = wr * 4 + m;
    h8 ha[4];
#pragma unroll
    for (int ks = 0; ks < 4; ++ks)
      ha[ks] = *(const h8*)&xa[(size_t)((mt * 4 + ks) * 64 + lane) * 8];
#pragma unroll
    for (int n = 0; n < 6; ++n)
#pragma unroll
      for (int ks = 0; ks < 4; ++ks)
        acc[m][n] = mfma_h(ha[ks], wb[n][ks], acc[m][n]);
  }

  // store: C row = m0+mt*16+kb*4+r, col = (wc*6+n)*16+row16
#pragma unroll
  for (int m = 0; m < 4; ++m) {
    const int mt = wr * 4 + m;
#pragma unroll
    for (int n = 0; n < 6; ++n) {
      const int c = (wc * 6 + n) * 16 + row16;
#pragma unroll
      for (int r = 0; r < 4; ++r) {
        const int row = m0 + mt * 16 + kb * 4 + r;
        gi[(size_t)row * G3_ + c] = (f16)(acc[m][n][r] + bias[n]);
      }
    }
  }
}

// ---------------------------------------------------------------- recurrence (MFMA, reg-prefetch)
// 64 blocks x 512 thr (8 waves), 16 batches/block. Wave w: gate cols
// j = w*16+(lane&15). gi/scores: per-thread register prefetch (private),
// raw s_barrier (no vmcnt drain) -> loads in flight across barrier.
template <int AUGRU>
__global__ __launch_bounds__(512, 1) void srec_mfma_kernel(
    const f16*  __restrict__ gi_all,   // [B*T,384]
    const int*  __restrict__ lens,
    const f16*  __restrict__ whhf,     // [24][4][64][8] B-fragments
    const float* __restrict__ bhh,
    const float* __restrict__ scores,  // AUGRU only
    f16*  __restrict__ interests_out,  // GRU only
    float* __restrict__ hout)          // AUGRU only
{
  __shared__ alignas(16) f16 h_lds[2][16 * H_];   // swizzled 16B slots

  const int tid = threadIdx.x;
  const int lane = tid & 63, wid = tid >> 6;
  const int bg = blockIdx.x * 16;
  const int row16 = lane & 15;
  const int kb = lane >> 4;
  const int jcol = wid * 16 + row16;
  const int brow0 = kb * 4;

  h8 wb[3][4];
#pragma unroll
  for (int g = 0; g < 3; ++g)
#pragma unroll
    for (int ks = 0; ks < 4; ++ks)
      wb[g][ks] = *(const h8*)(whhf + (size_t)(((g * 8 + wid) * 4 + ks) * 64 + lane) * 8);

  const float bh0 = bhh[jcol], bh1 = bhh[jcol + 128], bh2 = bhh[jcol + 256];
  int len4[4];
#pragma unroll
  for (int r = 0; r < 4; ++r) len4[r] = lens[bg + brow0 + r];
  float hk[4] = {0.f, 0.f, 0.f, 0.f};

  for (int i = tid; i < 16 * H_ / 2; i += 512) ((uint*)h_lds[0])[i] = 0u;

  // per-thread gi/score loads for step t -> registers (PRIVATE, no LDS)
  auto LOADG = [&](int t, f16 (&g)[12], float (&s)[4]) {
#pragma unroll
    for (int r = 0; r < 4; ++r) {
      const size_t base = ((size_t)(bg + brow0 + r) * T_ + t) * G3_;
      g[r * 3 + 0] = gi_all[base + jcol];
      g[r * 3 + 1] = gi_all[base + 128 + jcol];
      g[r * 3 + 2] = gi_all[base + 256 + jcol];
      if (AUGRU) s[r] = scores[(size_t)(bg + brow0 + r) * T_ + t];
    }
  };

  auto STEP = [&](int t, int p, f16 (&cur)[12], float (&scur)[4],
                  f16 (&nxt)[12], float (&snxt)[4]) {
    const int tn = (t + 1 < T_) ? (t + 1) : t;
    LOADG(tn, nxt, snxt);                       // in flight across the barrier

    h8 ha[4];
#pragma unroll
    for (int ks = 0; ks < 4; ++ks) {
      const int slot = (ks * 4 + kb) ^ row16;
      ha[ks] = *(const h8*)&h_lds[p][row16 * H_ + (slot & 15) * 8];
    }
    f32x4 a0 = {bh0, bh0, bh0, bh0};
    f32x4 a1 = {bh1, bh1, bh1, bh1};
    f32x4 a2 = {bh2, bh2, bh2, bh2};
#pragma unroll
    for (int ks = 0; ks < 4; ++ks) {
      a0 = mfma_h(ha[ks], wb[0][ks], a0);
      a1 = mfma_h(ha[ks], wb[1][ks], a1);
      a2 = mfma_h(ha[ks], wb[2][ks], a2);
    }
#pragma unroll
    for (int r = 0; r < 4; ++r) {
      const int row = brow0 + r;
      const float gir = (float)cur[r * 3 + 0];
      const float giz = (float)cur[r * 3 + 1];
      const float gin = (float)cur[r * 3 + 2];
      const float rr = sig_(gir + a0[r]);
      const float nn = tanh_(gin + rr * a2[r]);
      float hnew;
      if (AUGRU) {
        const float u = sig_(giz + a1[r]) * scur[r];
        hnew = (1.f - u) * hk[r] + u * nn;     // AUGRU: u gates NEW state
      } else {
        const float z = sig_(giz + a1[r]);
        hnew = (1.f - z) * nn + z * hk[r];     // torch GRU convention
      }
      if (t < len4[r]) hk[r] = hnew;
      const int slot = (jcol >> 3) ^ row;
      h_lds[p ^ 1][row * H_ + (slot & 15) * 8 + (jcol & 7)] = (f16)hk[r];
      if (!AUGRU)
        interests_out[((size_t)(bg + row) * T_ + t) * H_ + jcol] = (f16)hk[r];
    }
    // drain OUR ds_writes only (NOT vmcnt), then raw barrier.
    asm volatile("s_waitcnt lgkmcnt(0)" ::: "memory");
    __builtin_amdgcn_s_barrier();
    __builtin_amdgcn_sched_barrier(0);          // rule #18: pin ordering
  };

  f16 bufA[12], bufB[12];
  float sA[4] = {0, 0, 0, 0}, sB[4] = {0, 0, 0, 0};
  LOADG(0, bufA, sA);
  __syncthreads();      // one full drain: h_lds[0] zeros + t=0 loads visible

  for (int t = 0; t < T_; t += 2) {
    STEP(t,     0, bufA, sA, bufB, sB);
    STEP(t + 1, 1, bufB, sB, bufA, sA);
  }

  if (AUGRU) {
#pragma unroll
    for (int r = 0; r < 4; ++r)
      hout[(size_t)(bg + brow0 + r) * H_ + jcol] = hk[r];
  }
}

// ================================================================ fallback monolithic scan
template <int AUGRU>
__global__ __launch_bounds__(256, 1) void scan_kernel(
    const float* __restrict__ keys_f32,
    const f16*  __restrict__ x_f16,
    const int*  __restrict__ lens,
    const f16*  __restrict__ wih,
    const f16*  __restrict__ whh,
    const float* __restrict__ bih,
    const float* __restrict__ bhh,
    const float* __restrict__ scores,
    f16*  __restrict__ interests_out,
    float* __restrict__ hout,
    f16*  __restrict__ gi_all)
{
  __shared__ alignas(16) f16 wlds[G3_ * H_];
  __shared__ alignas(16) f16 xlds[CH_ * 4 * H_];
  __shared__ alignas(16) f16 hbuf[2][4 * H_];
  __shared__ float bihs[G3_];

  const int tid = threadIdx.x;
  const int b0 = blockIdx.x * 4;
  f16* gi_ws = gi_all + (size_t)blockIdx.x * (CH_ * 4 * G3_);

  for (int i = tid; i < G3_; i += 256) bihs[i] = bih[i];
  for (int i = tid; i < 2 * 4 * H_; i += 256) ((f16*)hbuf)[i] = (f16)0.f;
  {
    const uint4* src = (const uint4*)wih;
    uint4* dst = (uint4*)wlds;
    for (int idx = tid; idx < G3_ * H_ / 8; idx += 256) dst[idx] = src[idx];
  }

  const int j  = tid & 127;
  const int bp = tid >> 7;
  const int len0 = lens[b0 + bp];
  const int len1 = lens[b0 + bp + 2];
  const float bhr = bhh[j], bhz = bhh[j + 128], bhn = bhh[j + 256];
  const int mg = tid >> 4;
  const int n0 = tid & 15;

  H8U wr_r[16], wr_z[16], wr_n[16];
#pragma unroll
  for (int c = 0; c < 16; ++c) {
    wr_r[c].v = *(const h8*)(whh + (size_t)(j)       * H_ + c * 8);
    wr_z[c].v = *(const h8*)(whh + (size_t)(j + 128) * H_ + c * 8);
    wr_n[c].v = *(const h8*)(whh + (size_t)(j + 256) * H_ + c * 8);
  }

  float hreg[2] = {0.f, 0.f};
  int p = 0;
  __syncthreads();

  for (int t0 = 0; t0 < T_; t0 += CH_) {
    const int S = (T_ - t0 < CH_) ? (T_ - t0) : CH_;
    if (AUGRU) {
      const int NV = S * 4 * 16;
      for (int idx = tid; idx < NV; idx += 256) {
        int b = idx / (S * 16);
        int rem = idx - b * (S * 16);
        int tp = rem >> 4, c = rem & 15;
        const uint4* src = (const uint4*)(x_f16 + ((size_t)(b0 + b) * T_ + (t0 + tp)) * H_);
        ((uint4*)xlds)[(tp * 4 + b) * 16 + c] = src[c];
      }
    } else {
      const int NV = S * 4 * 32;
      for (int idx = tid; idx < NV; idx += 256) {
        int b = idx / (S * 32);
        int rem = idx - b * (S * 32);
        int tp = rem >> 5, c = rem & 31;
        const float4* src = (const float4*)(keys_f32 + ((size_t)(b0 + b) * T_ + (t0 + tp)) * H_);
        float4 v = src[c];
        f16* dst = &xlds[(tp * 4 + b) * H_ + c * 4];
        dst[0] = (f16)v.x; dst[1] = (f16)v.y; dst[2] = (f16)v.z; dst[3] = (f16)v.w;
      }
    }
    __syncthreads();
    for (int ngrp = 0; ngrp < 3; ++ngrp) {
      float acc[8][8];
#pragma unroll
      for (int a = 0; a < 8; ++a)
#pragma unroll
        for (int c = 0; c < 8; ++c) acc[a][c] = 0.f;
      for (int kc = 0; kc < 16; ++kc) {
        const int kcp = (kc + n0) & 15;
        H8U xr[8], wr[8];
#pragma unroll
        for (int mi = 0; mi < 8; ++mi)
          xr[mi].v = *(const h8*)&xlds[(mg * 8 + mi) * H_ + kcp * 8];
#pragma unroll
        for (int ni = 0; ni < 8; ++ni)
          wr[ni].v = *(const h8*)&wlds[(n0 * 24 + ngrp * 8 + ni) * H_ + kcp * 8];
#pragma unroll
        for (int mi = 0; mi < 8; ++mi)
#pragma unroll
          for (int ni = 0; ni < 8; ++ni)
#pragma unroll
            for (int q = 0; q < 4; ++q)
              acc[mi][ni] = dot2a(xr[mi].p[q], wr[ni].p[q], acc[mi][ni]);
      }
#pragma unroll
      for (int mi = 0; mi < 8; ++mi) {
        const int pr = mg * 8 + mi;
        if (pr < S * 4) {
          H8U o8;
#pragma unroll
          for (int ni = 0; ni < 8; ++ni) {
            const int g = n0 * 24 + ngrp * 8 + ni;
            o8.p[ni >> 1][ni & 1] = (f16)(acc[mi][ni] + bihs[g]);
          }
          *(h8*)&gi_ws[(size_t)pr * G3_ + n0 * 24 + ngrp * 8] = o8.v;
        }
      }
    }
    __syncthreads();
    for (int tp = 0; tp < S; ++tp) {
      const int t = t0 + tp;
      float hr[2] = {0.f, 0.f}, hz[2] = {0.f, 0.f}, hn[2] = {0.f, 0.f};
#pragma unroll
      for (int kc = 0; kc < 16; ++kc) {
        H8U hv0, hv1;
        hv0.v = *(const h8*)&hbuf[p][(bp)     * H_ + kc * 8];
        hv1.v = *(const h8*)&hbuf[p][(bp + 2) * H_ + kc * 8];
#pragma unroll
        for (int q = 0; q < 4; ++q) {
          hr[0] = dot2a(wr_r[kc].p[q], hv0.p[q], hr[0]);
          hz[0] = dot2a(wr_z[kc].p[q], hv0.p[q], hz[0]);
          hn[0] = dot2a(wr_n[kc].p[q], hv0.p[q], hn[0]);
          hr[1] = dot2a(wr_r[kc].p[q], hv1.p[q], hr[1]);
          hz[1] = dot2a(wr_z[kc].p[q], hv1.p[q], hz[1]);
          hn[1] = dot2a(wr_n[kc].p[q], hv1.p[q], hn[1]);
        }
      }
#pragma unroll
      for (int bb = 0; bb < 2; ++bb) {
        const int b = bp + bb * 2;
        const int gb = b0 + b;
        const f16* gi = &gi_ws[(size_t)(tp * 4 + b) * G3_];
        const float gr  = (float)gi[j]       + hr[bb] + bhr;
        const float gz  = (float)gi[j + 128] + hz[bb] + bhz;
        const float gin = (float)gi[j + 256];
        const float r = sig_(gr);
        const float nn = tanh_(gin + r * (hn[bb] + bhn));
        float hnew;
        if (AUGRU) {
          const float a = scores[(size_t)gb * T_ + t];
          const float u = sig_(gz) * a;
          hnew = (1.f - u) * hreg[bb] + u * nn;
        } else {
          const float z = sig_(gz);
          hnew = (1.f - z) * nn + z * hreg[bb];
        }
        const int mylen = bb ? len1 : len0;
        if (t < mylen) hreg[bb] = hnew;
        hbuf[p ^ 1][b * H_ + j] = (f16)hreg[bb];
        if (!AUGRU) interests_out[((size_t)gb * T_ + t) * H_ + j] = (f16)hreg[bb];
      }
      __syncthreads();
      p ^= 1;
    }
  }
  if (AUGRU) {
    hout[(size_t)(b0 + bp) * H_ + j]     = hreg[0];
    hout[(size_t)(b0 + bp + 2) * H_ + j] = hreg[1];
  }
}

// ---------------------------------------------------------------- attention (MFMA, softmax fused)
__global__ __launch_bounds__(512, 1) void attn_kernel(
    const float* __restrict__ query,
    const f16* __restrict__ interests,
    const f16* __restrict__ wf1g,
    const f16* __restrict__ wf2g,
    const f16* __restrict__ wfg,
    const float* __restrict__ qdotp,
    const float* __restrict__ b2,
    const float* __restrict__ bfp,
    const int* __restrict__ lens,
    float* __restrict__ scores)
{
  __shared__ alignas(16) f16 wf1[NT1 * 8 * 64 * 8];
  __shared__ alignas(16) f16 wf2[NT2 * KS2N * 64 * 8];
  __shared__ alignas(16) f16 uni[29952];
  __shared__ alignas(16) f16 qh[128];
  __shared__ alignas(16) f16 wfv[40];
  __shared__ float qd[80];
  __shared__ float b2s[40];
  __shared__ float red[256];

  f16* ktf = uni;
  f16* h1f = uni;
  f16* h2s = uni + MT1 * KS2N * 64 * 8;

  const int tid = threadIdx.x;
  const int b = blockIdx.x;
  const int lane = tid & 63, wid = tid >> 6;
  const int row = lane & 15, kb = lane >> 4;

  for (int idx = tid; idx < NT1 * 8 * 64; idx += 512)
    ((uint4*)wf1)[idx] = ((const uint4*)wf1g)[idx];
  for (int idx = tid; idx < NT2 * KS2N * 64; idx += 512)
    ((uint4*)wf2)[idx] = ((const uint4*)wf2g)[idx];
  for (int idx = tid; idx < MT1 * 4 * 64; idx += 512) {
    const int l = idx & 63, ks = (idx >> 6) & 3, mt = idx >> 8;
    const int t = mt * 16 + (l & 15);
    uint4 v = make_uint4(0u, 0u, 0u, 0u);
    if (t < T_)
      v = *(const uint4*)(interests + ((size_t)b * T_ + t) * H_ + ks * 32 + ((l >> 4) << 3));
    ((uint4*)ktf)[idx] = v;
  }
  if (tid < 32) {
    float4 qv = ((const float4*)(query + (size_t)b * H_))[tid];
    f16* d = &qh[tid * 4];
    d[0] = (f16)qv.x; d[1] = (f16)qv.y; d[2] = (f16)qv.z; d[3] = (f16)qv.w;
  }
  if (tid < 80) qd[tid] = qdotp[(size_t)b * 80 + tid];
  if (tid >= 128 && tid < 168) wfv[tid - 128] = wfg[tid - 128];
  if (tid >= 192 && tid < 232) b2s[tid - 192] = b2[tid - 192];
  __syncthreads();

  const int nmt = (wid + 8 < MT1) ? 2 : 1;
  const int mts[2] = { wid, wid + 8 };

  h8 qf[4];
#pragma unroll
  for (int h = 0; h < 4; ++h) qf[h] = *(const h8*)&qh[h * 32 + kb * 8];

  h8 afr[2][4], qa[2][4];
#pragma unroll
  for (int m = 0; m < 2; ++m) if (m < nmt) {
#pragma unroll
    for (int ks = 0; ks < 4; ++ks) {
      afr[m][ks] = *(const h8*)&ktf[((mts[m] * 4 + ks) * 64 + lane) * 8];
      qa[m][ks] = afr[m][ks] * qf[ks];
    }
  }
  __syncthreads();

  f32x4 acc[2][NT1];
#pragma unroll
  for (int m = 0; m < 2; ++m)
#pragma unroll
    for (int n = 0; n < NT1; ++n) acc[m][n] = (f32x4){0.f, 0.f, 0.f, 0.f};

  for (int nt = 0; nt < NT1; ++nt) {
#pragma unroll
    for (int ks = 0; ks < 8; ++ks) {
      const h8 bfr = *(const h8*)&wf1[((nt * 8 + ks) * 64 + lane) * 8];
#pragma unroll
      for (int m = 0; m < 2; ++m) if (m < nmt)
        acc[m][nt] = mfma_h(ks < 4 ? afr[m][ks] : qa[m][ks - 4], bfr, acc[m][nt]);
    }
  }

#pragma unroll
  for (int m = 0; m < 2; ++m) if (m < nmt) {
    const int mt = mts[m];
#pragma unroll
    for (int nt = 0; nt < NT1; ++nt) {
      const int o = nt * 16 + row;
      const float qdo = qd[o];
#pragma unroll
      for (int r = 0; r < 4; ++r) {
        const float val = sig_(acc[m][nt][r] + qdo);
        const int lr = kb * 4 + r;
        const int ks2 = o >> 5, kb2 = (o >> 3) & 3, i2 = o & 7;
        h1f[((mt * KS2N + ks2) * 64 + (lr | (kb2 << 4))) * 8 + i2] = (f16)val;
      }
    }
  }
  for (int idx = tid; idx < MT1 * 32 * 8; idx += 512) {
    const int mt = idx >> 8, rr = idx & 255;
    h1f[((mt * KS2N + 2) * 64 + 32 + (rr >> 3)) * 8 + (rr & 7)] = (f16)0.f;
  }
  __syncthreads();

  h8 a2[2][KS2N];
#pragma unroll
  for (int m = 0; m < 2; ++m) if (m < nmt)
#pragma unroll
    for (int ks = 0; ks < KS2N; ++ks)
      a2[m][ks] = *(const h8*)&h1f[((mts[m] * KS2N + ks) * 64 + lane) * 8];

  f32x4 acc2[2][NT2];
#pragma unroll
  for (int m = 0; m < 2; ++m)
#pragma unroll
    for (int n = 0; n < NT2; ++n) acc2[m][n] = (f32x4){0.f, 0.f, 0.f, 0.f};

#pragma unroll
  for (int nt = 0; nt < NT2; ++nt)
#pragma unroll
    for (int ks = 0; ks < KS2N; ++ks) {
      const h8 bfr = *(const h8*)&wf2[((nt * KS2N + ks) * 64 + lane) * 8];
#pragma unroll
      for (int m = 0; m < 2; ++m) if (m < nmt)
        acc2[m][nt] = mfma_h(a2[m][ks], bfr, acc2[m][nt]);
    }

#pragma unroll
  for (int m = 0; m < 2; ++m) if (m < nmt) {
#pragma unroll
    for (int nt = 0; nt < NT2; ++nt) {
      const int o2 = nt * 16 + row;
      if (o2 < 40) {
        const float bo = b2s[o2];
#pragma unroll
        for (int r = 0; r < 4; ++r) {
          const int t = mts[m] * 16 + kb * 4 + r;
          h2s[t * 48 + o2] = (f16)sig_(acc2[m][nt][r] + bo);
        }
      }
    }
  }
  __syncthreads();

  float logit = 0.f;
  if (tid < T_) {
    float a = 0.f;
#pragma unroll
    for (int c = 0; c < 5; ++c) {
      H8U wv, hv;
      wv.v = *(const h8*)&wfv[c * 8];
      hv.v = *(const h8*)&h2s[tid * 48 + c * 8];
#pragma unroll
      for (int q = 0; q < 4; ++q) a = dot2a(wv.p[q], hv.p[q], a);
    }
    logit = (a + bfp[0]) * 0.088388347648318447f;
  }
  const int len = lens[b];
  if (tid < 256) red[tid] = (tid < T_ && tid < len) ? logit : -1e30f;
  __syncthreads();
  for (int s = 128; s > 0; s >>= 1) {
    if (tid < s) red[tid] = fmaxf(red[tid], red[tid + s]);
    __syncthreads();
  }
  const float mx = red[0];
  __syncthreads();
  const float e = (tid < T_ && tid < len) ? __expf(logit - mx) : 0.f;
  if (tid < 256) red[tid] = e;
  __syncthreads();
  for (int s = 128; s > 0; s >>= 1) {
    if (tid < s) red[tid] += red[tid + s];
    __syncthreads();
  }
  if (tid < T_) scores[(size_t)b * T_ + tid] = e * (1.f / red[0]);
}

// ---------------------------------------------------------------- launcher
extern "C" void kernel_launch(void* const* d_in, const int* in_sizes, int n_in,
                              void* d_out, int out_size, void* d_ws, size_t ws_size,
                              hipStream_t stream)
{
  (void)in_sizes; (void)n_in; (void)out_size;
  const float* query = (const float*)d_in[0];
  const float* keys  = (const float*)d_in[1];
  const int*   lens  = (const int*)d_in[2];
  const float* Wih_e = (const float*)d_in[3];
  const float* Whh_e = (const float*)d_in[4];
  const float* bih_e = (const float*)d_in[5];
  const float* bhh_e = (const float*)d_in[6];
  const float* Wih_a = (const float*)d_in[7];
  const float* Whh_a = (const float*)d_in[8];
  const float* bih_a = (const float*)d_in[9];
  const float* bhh_a = (const float*)d_in[10];
  const float* W1 = (const float*)d_in[11];
  const float* b1 = (const float*)d_in[12];
  const float* W2 = (const float*)d_in[13];
  const float* b2 = (const float*)d_in[14];
  const float* Wf = (const float*)d_in[15];
  const float* bf = (const float*)d_in[16];

  char* w = (char*)d_ws;
  size_t off = 0;
  auto take = [&](size_t bytes) { char* p = w + off; off += (bytes + 255) & ~(size_t)255; return p; };

  f16*   interests = (f16*)take((size_t)B_ * T_ * H_ * 2);
  float* scores    = (float*)take((size_t)B_ * T_ * 4);
  f16*   wih_e_h = (f16*)take(G3_ * H_ * 2);
  f16*   whh_e_h = (f16*)take(G3_ * H_ * 2);
  f16*   wih_a_h = (f16*)take(G3_ * H_ * 2);
  f16*   whh_a_h = (f16*)take(G3_ * H_ * 2);
  float* A1f = (float*)take(80 * 128 * 4);
  f16*   Wfh = (f16*)take(64 * 2);
  f16*   wf1p = (f16*)take(NT1 * 8 * 64 * 8 * 2);
  f16*   wf2p = (f16*)take(NT2 * KS2N * 64 * 8 * 2);
  f16*   whhf_e = (f16*)take(WHHF_ELEMS * 2);
  f16*   whhf_a = (f16*)take(WHHF_ELEMS * 2);
  f16*   wihf_e = (f16*)take(WHHF_ELEMS * 2);
  f16*   wihf_a = (f16*)take(WHHF_ELEMS * 2);
  float* qdotp = (float*)take((size_t)B_ * 80 * 4);

  const size_t small_off = off;
  f16* gi_big = (f16*)take((size_t)B_ * T_ * G3_ * 2);
  const size_t need_big = off;
  const bool big = (ws_size >= need_big);
  off = small_off;
  f16* gi_ws = (f16*)take((size_t)SCAN_BLOCKS * CH_ * 4 * G3_ * 2);

  const int prep_tasks = 4 * G3_ * H_ + 80 * 128 + 40
                       + NT1 * 8 * 64 * 8 + NT2 * KS2N * 64 * 8
                       + 4 * WHHF_ELEMS;
  prep_kernel<<<(prep_tasks + 255) / 256, 256, 0, stream>>>(
      Wih_e, Whh_e, Wih_a, Whh_a, W1, W2, Wf,
      wih_e_h, whh_e_h, wih_a_h, whh_a_h, A1f, Wfh, wf1p, wf2p,
      whhf_e, whhf_a, wihf_e, wihf_a);
  qdot_kernel<<<B_, 128, 0, stream>>>(query, A1f, b1, qdotp);

  if (big) {
    gi_gemm_mfma_kernel<1><<<B_ * T_ / 128, 512, 0, stream>>>(
        keys, (const f16*)nullptr, wihf_e, bih_e, gi_big);
    srec_mfma_kernel<0><<<B_ / 16, 512, 0, stream>>>(
        gi_big, lens, whhf_e, bhh_e, (const float*)nullptr, interests, (float*)nullptr);
    attn_kernel<<<B_, 512, 0, stream>>>(
        query, interests, wf1p, wf2p, Wfh, qdotp, b2, bf, lens, scores);
    gi_gemm_mfma_kernel<0><<<B_ * T_ / 128, 512, 0, stream>>>(
        (const float*)nullptr, interests, wihf_a, bih_a, gi_big);
    srec_mfma_kernel<1><<<B_ / 16, 512, 0, stream>>>(
        gi_big, lens, whhf_a, bhh_a, scores, (f16*)nullptr, (float*)d_out);
  } else {
    scan_kernel<0><<<SCAN_BLOCKS, 256, 0, stream>>>(
        keys, (const f16*)nullptr, lens, wih_e_h, whh_e_h, bih_e, bhh_e,
        (const float*)nullptr, interests, (float*)nullptr, gi_ws);
    attn_kernel<<<B_, 512, 0, stream>>>(
        query, interests, wf1p, wf2p, Wfh, qdotp, b2, bf, lens, scores);
    scan_kernel<1><<<SCAN_BLOCKS, 256, 0, stream>>>(
        (const float*)nullptr, interests, lens, wih_a_h, whh_a_h, bih_a, bhh_a,
        scores, (f16*)nullptr, (float*)d_out, gi_ws);
  }
}

// Round 8
// 817.763 us; speedup vs baseline: 1.3826x; 1.0085x over previous
//
#include <hip/hip_runtime.h>
#include <hip/hip_fp16.h>
#include <stdint.h>

// DIEN (GRU -> DIN attention -> AUGRU) on MI355X.
// R7 (resubmit after GPU-acquisition timeout; source unchanged):
// srec sync fix. R6's asm("s_waitcnt lgkmcnt(0)":::"memory") made the
// waitcnt pass drain vmcnt(0) each step (unknown-memory asm) -> prefetch dead.
// Now: sched_barrier(0) + __builtin_amdgcn_s_waitcnt(0xC07F = lgkmcnt(0) only)
// + raw s_barrier; gi/scores prefetched 2 steps ahead in 3 named register
// buffers (unroll-3 loop). gi_gemm(MFMA), attn(MFMA+fused softmax), prep,
// qdot unchanged from R6.

#define B_   1024
#define T_   200
#define H_   128
#define G3_  384
#define CH_  32
#define SCAN_BLOCKS 256

#define MT1  13
#define NT1  5
#define NT2  3
#define KS2N 3

#define WHHF_ELEMS (24 * 4 * 64 * 8)   // 49152 f16 per [384][128] frag pack

typedef _Float16 f16;
typedef _Float16 h2 __attribute__((ext_vector_type(2)));
typedef _Float16 h8 __attribute__((ext_vector_type(8)));
typedef float f32x4 __attribute__((ext_vector_type(4)));

union H8U { h8 v; h2 p[4]; };

#define USE_FDOT2 1

__device__ __forceinline__ float dot2a(h2 a, h2 b, float acc) {
#if USE_FDOT2
  return __builtin_amdgcn_fdot2(a, b, acc, false);
#else
  return fmaf((float)a[1], (float)b[1], fmaf((float)a[0], (float)b[0], acc));
#endif
}

__device__ __forceinline__ f32x4 mfma_h(h8 a, h8 b, f32x4 c) {
  return __builtin_amdgcn_mfma_f32_16x16x32_f16(a, b, c, 0, 0, 0);
}

__device__ __forceinline__ float sig_(float x)  { return 1.f / (1.f + __expf(-x)); }
__device__ __forceinline__ float tanh_(float x) { return 1.f - 2.f / (__expf(2.f * x) + 1.f); }

// ---------------------------------------------------------------- prep
__global__ void prep_kernel(
    const float* __restrict__ Wih_e, const float* __restrict__ Whh_e,
    const float* __restrict__ Wih_a, const float* __restrict__ Whh_a,
    const float* __restrict__ W1, const float* __restrict__ W2,
    const float* __restrict__ Wf,
    f16* __restrict__ wih_e_h, f16* __restrict__ whh_e_h,
    f16* __restrict__ wih_a_h, f16* __restrict__ whh_a_h,
    float* __restrict__ A1f, f16* __restrict__ Wfh,
    f16* __restrict__ wf1p, f16* __restrict__ wf2p,
    f16* __restrict__ whhf_e, f16* __restrict__ whhf_a,
    f16* __restrict__ wihf_e, f16* __restrict__ wihf_a)
{
  int i = blockIdx.x * 256 + threadIdx.x;
  const int NW = G3_ * H_;
  if (i < NW) { wih_e_h[i] = (f16)Wih_e[i]; return; }  i -= NW;
  if (i < NW) { whh_e_h[i] = (f16)Whh_e[i]; return; }  i -= NW;
  if (i < NW) { wih_a_h[i] = (f16)Wih_a[i]; return; }  i -= NW;
  if (i < NW) { whh_a_h[i] = (f16)Whh_a[i]; return; }  i -= NW;
  const int NB = 80 * 128;
  if (i < NB) { int o = i >> 7, jj = i & 127;
    A1f[i] = W1[o * 512 + jj] + W1[o * 512 + 256 + jj]; return; }  i -= NB;
  if (i < 40) { Wfh[i] = (f16)Wf[i]; return; }  i -= 40;
  if (i < NT1 * 8 * 64 * 8) {
    const int ii = i & 7, lane = (i >> 3) & 63, ks = (i >> 9) & 7, nt = i >> 12;
    const int kk = ks * 32 + ((lane >> 4) << 3) + ii;
    const int o = nt * 16 + (lane & 15);
    float v;
    if (kk < 128) v = W1[o * 512 + 128 + kk] - W1[o * 512 + 256 + kk];
    else          v = W1[o * 512 + 384 + (kk - 128)];
    wf1p[i] = (f16)v; return;
  }  i -= NT1 * 8 * 64 * 8;
  if (i < NT2 * KS2N * 64 * 8) {
    const int ii = i & 7, lane = (i >> 3) & 63, rem = i >> 9;
    const int ks = rem % KS2N, nt = rem / KS2N;
    const int k = ks * 32 + ((lane >> 4) << 3) + ii;
    const int o2 = nt * 16 + (lane & 15);
    wf2p[i] = (k < 80 && o2 < 40) ? (f16)W2[o2 * 80 + k] : (f16)0.f;
    return;
  }  i -= NT2 * KS2N * 64 * 8;
  // generic [384][128] -> B-fragment packs: value = W[nt*16+(lane&15)][ks*32+(lane>>4)*8+ii]
  if (i < 4 * WHHF_ELEMS) {
    const int set = i / WHHF_ELEMS;
    const int r = i - set * WHHF_ELEMS;
    const int ii = r & 7, lane = (r >> 3) & 63, ks = (r >> 9) & 3, nt = r >> 11;
    const int row = nt * 16 + (lane & 15);
    const int col = ks * 32 + ((lane >> 4) << 3) + ii;
    const float* W = (set == 0) ? Whh_e : (set == 1) ? Whh_a : (set == 2) ? Wih_e : Wih_a;
    f16* D = (set == 0) ? whhf_e : (set == 1) ? whhf_a : (set == 2) ? wihf_e : wihf_a;
    D[r] = (f16)W[row * H_ + col];
  }
}

// qdot[b][o] = b1[o] + sum_j A1[o][j] * q[b][j]
__global__ void qdot_kernel(const float* __restrict__ query, const float* __restrict__ A1f,
                            const float* __restrict__ b1, float* __restrict__ qdotp)
{
  const int b = blockIdx.x, o = threadIdx.x;
  if (o >= 80) return;
  float acc = b1[o];
  const float* qa = query + b * H_;
  const float* aa = A1f + o * H_;
  for (int jj = 0; jj < H_; ++jj) acc = fmaf(aa[jj], qa[jj], acc);
  qdotp[b * 80 + o] = acc;
}

// ---------------------------------------------------------------- gi GEMM (MFMA)
template <int XF32>
__global__ __launch_bounds__(512, 1) void gi_gemm_mfma_kernel(
    const float* __restrict__ xf32,   // XF32: [M,128] f32
    const f16*  __restrict__ xh,      // else: [M,128] f16
    const f16*  __restrict__ wihf,    // [24][4][64][8] B-fragments
    const float* __restrict__ bih,
    f16* __restrict__ gi)             // [M,384]
{
  __shared__ alignas(16) f16 xa[8 * 4 * 64 * 8];   // 32KB A-fragments
  const int tid = threadIdx.x;
  const int lane = tid & 63, wid = tid >> 6;
  const int m0 = blockIdx.x * 128;
  const int row16 = lane & 15, kb = lane >> 4;
  const int wr = wid >> 2, wc = wid & 3;

  h8 wb[6][4];
#pragma unroll
  for (int n = 0; n < 6; ++n)
#pragma unroll
    for (int ks = 0; ks < 4; ++ks)
      wb[n][ks] = *(const h8*)(wihf + (size_t)(((wc * 6 + n) * 4 + ks) * 64 + lane) * 8);
  float bias[6];
#pragma unroll
  for (int n = 0; n < 6; ++n) bias[n] = bih[(wc * 6 + n) * 16 + row16];

  for (int s = tid; s < 2048; s += 512) {
    const int l = s & 63, ks = (s >> 6) & 3, mt = s >> 8;
    const int row = m0 + mt * 16 + (l & 15);
    const int col = ks * 32 + ((l >> 4) << 3);
    if (XF32) {
      const float* src = xf32 + (size_t)row * H_ + col;
      float4 v0 = *(const float4*)(src);
      float4 v1 = *(const float4*)(src + 4);
      f16 t8[8] = {(f16)v0.x, (f16)v0.y, (f16)v0.z, (f16)v0.w,
                   (f16)v1.x, (f16)v1.y, (f16)v1.z, (f16)v1.w};
      *(uint4*)&xa[s * 8] = *(const uint4*)t8;
    } else {
      *(uint4*)&xa[s * 8] = *(const uint4*)(xh + (size_t)row * H_ + col);
    }
  }
  __syncthreads();

  f32x4 acc[4][6];
#pragma unroll
  for (int m = 0; m < 4; ++m)
#pragma unroll
    for (int n = 0; n < 6; ++n) acc[m][n] = (f32x4){0.f, 0.f, 0.f, 0.f};

#pragma unroll
  for (int m = 0; m < 4; ++m) {
    const int mt = wr * 4 + m;
    h8 ha[4];
#pragma unroll
    for (int ks = 0; ks < 4; ++ks)
      ha[ks] = *(const h8*)&xa[(size_t)((mt * 4 + ks) * 64 + lane) * 8];
#pragma unroll
    for (int n = 0; n < 6; ++n)
#pragma unroll
      for (int ks = 0; ks < 4; ++ks)
        acc[m][n] = mfma_h(ha[ks], wb[n][ks], acc[m][n]);
  }

#pragma unroll
  for (int m = 0; m < 4; ++m) {
    const int mt = wr * 4 + m;
#pragma unroll
    for (int n = 0; n < 6; ++n) {
      const int c = (wc * 6 + n) * 16 + row16;
#pragma unroll
      for (int r = 0; r < 4; ++r) {
        const int row = m0 + mt * 16 + kb * 4 + r;
        gi[(size_t)row * G3_ + c] = (f16)(acc[m][n][r] + bias[n]);
      }
    }
  }
}

// ---------------------------------------------------------------- recurrence (MFMA, deep reg-prefetch)
// 64 blocks x 512 thr (8 waves), 16 batches/block. Wave w: gate cols
// j = w*16+(lane&15). gi/scores prefetched DEPTH-2 in 3 named register
// buffers; barrier = sched_barrier + s_waitcnt(lgkmcnt(0) ONLY, builtin —
// no asm memory clobber, so vmcnt prefetch survives) + raw s_barrier.
template <int AUGRU>
__global__ __launch_bounds__(512, 1) void srec_mfma_kernel(
    const f16*  __restrict__ gi_all,   // [B*T,384]
    const int*  __restrict__ lens,
    const f16*  __restrict__ whhf,     // [24][4][64][8] B-fragments
    const float* __restrict__ bhh,
    const float* __restrict__ scores,  // AUGRU only
    f16*  __restrict__ interests_out,  // GRU only
    float* __restrict__ hout)          // AUGRU only
{
  __shared__ alignas(16) f16 h_lds[2][16 * H_];   // swizzled 16B slots

  const int tid = threadIdx.x;
  const int lane = tid & 63, wid = tid >> 6;
  const int bg = blockIdx.x * 16;
  const int row16 = lane & 15;
  const int kb = lane >> 4;
  const int jcol = wid * 16 + row16;
  const int brow0 = kb * 4;

  h8 wb[3][4];
#pragma unroll
  for (int g = 0; g < 3; ++g)
#pragma unroll
    for (int ks = 0; ks < 4; ++ks)
      wb[g][ks] = *(const h8*)(whhf + (size_t)(((g * 8 + wid) * 4 + ks) * 64 + lane) * 8);

  const float bh0 = bhh[jcol], bh1 = bhh[jcol + 128], bh2 = bhh[jcol + 256];
  int len4[4];
#pragma unroll
  for (int r = 0; r < 4; ++r) len4[r] = lens[bg + brow0 + r];
  float hk[4] = {0.f, 0.f, 0.f, 0.f};

  for (int i = tid; i < 16 * H_ / 2; i += 512) ((uint*)h_lds[0])[i] = 0u;

  // per-thread gi/score loads for step t -> registers (PRIVATE)
  auto LOADG = [&](int t, f16 (&g)[12], float (&s)[4]) {
#pragma unroll
    for (int r = 0; r < 4; ++r) {
      const size_t base = ((size_t)(bg + brow0 + r) * T_ + t) * G3_;
      g[r * 3 + 0] = gi_all[base + jcol];
      g[r * 3 + 1] = gi_all[base + 128 + jcol];
      g[r * 3 + 2] = gi_all[base + 256 + jcol];
      if (AUGRU) s[r] = scores[(size_t)(bg + brow0 + r) * T_ + t];
    }
  };

  auto STEP = [&](int t, f16 (&cur)[12], float (&scur)[4],
                  f16 (&nxt)[12], float (&snxt)[4]) {
    const int p = t & 1;
    const int tn = (t + 2 < T_) ? (t + 2) : (T_ - 1);
    LOADG(tn, nxt, snxt);                       // stays in flight across barriers

    h8 ha[4];
#pragma unroll
    for (int ks = 0; ks < 4; ++ks) {
      const int slot = (ks * 4 + kb) ^ row16;
      ha[ks] = *(const h8*)&h_lds[p][row16 * H_ + (slot & 15) * 8];
    }
    f32x4 a0 = {bh0, bh0, bh0, bh0};
    f32x4 a1 = {bh1, bh1, bh1, bh1};
    f32x4 a2 = {bh2, bh2, bh2, bh2};
#pragma unroll
    for (int ks = 0; ks < 4; ++ks) {
      a0 = mfma_h(ha[ks], wb[0][ks], a0);
      a1 = mfma_h(ha[ks], wb[1][ks], a1);
      a2 = mfma_h(ha[ks], wb[2][ks], a2);
    }
#pragma unroll
    for (int r = 0; r < 4; ++r) {
      const int row = brow0 + r;
      const float gir = (float)cur[r * 3 + 0];
      const float giz = (float)cur[r * 3 + 1];
      const float gin = (float)cur[r * 3 + 2];
      const float rr = sig_(gir + a0[r]);
      const float nn = tanh_(gin + rr * a2[r]);
      float hnew;
      if (AUGRU) {
        const float u = sig_(giz + a1[r]) * scur[r];
        hnew = (1.f - u) * hk[r] + u * nn;     // AUGRU: u gates NEW state
      } else {
        const float z = sig_(giz + a1[r]);
        hnew = (1.f - z) * nn + z * hk[r];     // torch GRU convention
      }
      if (t < len4[r]) hk[r] = hnew;
      const int slot = (jcol >> 3) ^ row;
      h_lds[p ^ 1][row * H_ + (slot & 15) * 8 + (jcol & 7)] = (f16)hk[r];
      if (!AUGRU)
        interests_out[((size_t)(bg + row) * T_ + t) * H_ + jcol] = (f16)hk[r];
    }
    // Pin order, drain ONLY lgkm (ds_writes), raw barrier (no vmcnt drain).
    // 0xC07F: vmcnt=63 (bits[3:0]=0xF,[15:14]=3), expcnt=7, lgkmcnt=0.
    __builtin_amdgcn_sched_barrier(0);
    __builtin_amdgcn_s_waitcnt(0xC07F);
    __builtin_amdgcn_s_barrier();
    __builtin_amdgcn_sched_barrier(0);
  };

  f16 bufA[12], bufB[12], bufC[12];
  float sA[4] = {0, 0, 0, 0}, sB[4] = {0, 0, 0, 0}, sC[4] = {0, 0, 0, 0};
  LOADG(0, bufA, sA);
  LOADG(1, bufB, sB);
  __syncthreads();      // startup drain: h_lds zeros + t=0/1 loads visible

  for (int t = 0; t < 198; t += 3) {          // 66 iterations, t = 0..197
    STEP(t,     bufA, sA, bufC, sC);          // loads t+2 -> C
    STEP(t + 1, bufB, sB, bufA, sA);          // loads t+3 -> A
    STEP(t + 2, bufC, sC, bufB, sB);          // loads t+4 -> B
  }
  STEP(198, bufA, sA, bufC, sC);
  STEP(199, bufB, sB, bufA, sA);

  if (AUGRU) {
#pragma unroll
    for (int r = 0; r < 4; ++r)
      hout[(size_t)(bg + brow0 + r) * H_ + jcol] = hk[r];
  }
}

// ================================================================ fallback monolithic scan
template <int AUGRU>
__global__ __launch_bounds__(256, 1) void scan_kernel(
    const float* __restrict__ keys_f32,
    const f16*  __restrict__ x_f16,
    const int*  __restrict__ lens,
    const f16*  __restrict__ wih,
    const f16*  __restrict__ whh,
    const float* __restrict__ bih,
    const float* __restrict__ bhh,
    const float* __restrict__ scores,
    f16*  __restrict__ interests_out,
    float* __restrict__ hout,
    f16*  __restrict__ gi_all)
{
  __shared__ alignas(16) f16 wlds[G3_ * H_];
  __shared__ alignas(16) f16 xlds[CH_ * 4 * H_];
  __shared__ alignas(16) f16 hbuf[2][4 * H_];
  __shared__ float bihs[G3_];

  const int tid = threadIdx.x;
  const int b0 = blockIdx.x * 4;
  f16* gi_ws = gi_all + (size_t)blockIdx.x * (CH_ * 4 * G3_);

  for (int i = tid; i < G3_; i += 256) bihs[i] = bih[i];
  for (int i = tid; i < 2 * 4 * H_; i += 256) ((f16*)hbuf)[i] = (f16)0.f;
  {
    const uint4* src = (const uint4*)wih;
    uint4* dst = (uint4*)wlds;
    for (int idx = tid; idx < G3_ * H_ / 8; idx += 256) dst[idx] = src[idx];
  }

  const int j  = tid & 127;
  const int bp = tid >> 7;
  const int len0 = lens[b0 + bp];
  const int len1 = lens[b0 + bp + 2];
  const float bhr = bhh[j], bhz = bhh[j + 128], bhn = bhh[j + 256];
  const int mg = tid >> 4;
  const int n0 = tid & 15;

  H8U wr_r[16], wr_z[16], wr_n[16];
#pragma unroll
  for (int c = 0; c < 16; ++c) {
    wr_r[c].v = *(const h8*)(whh + (size_t)(j)       * H_ + c * 8);
    wr_z[c].v = *(const h8*)(whh + (size_t)(j + 128) * H_ + c * 8);
    wr_n[c].v = *(const h8*)(whh + (size_t)(j + 256) * H_ + c * 8);
  }

  float hreg[2] = {0.f, 0.f};
  int p = 0;
  __syncthreads();

  for (int t0 = 0; t0 < T_; t0 += CH_) {
    const int S = (T_ - t0 < CH_) ? (T_ - t0) : CH_;
    if (AUGRU) {
      const int NV = S * 4 * 16;
      for (int idx = tid; idx < NV; idx += 256) {
        int b = idx / (S * 16);
        int rem = idx - b * (S * 16);
        int tp = rem >> 4, c = rem & 15;
        const uint4* src = (const uint4*)(x_f16 + ((size_t)(b0 + b) * T_ + (t0 + tp)) * H_);
        ((uint4*)xlds)[(tp * 4 + b) * 16 + c] = src[c];
      }
    } else {
      const int NV = S * 4 * 32;
      for (int idx = tid; idx < NV; idx += 256) {
        int b = idx / (S * 32);
        int rem = idx - b * (S * 32);
        int tp = rem >> 5, c = rem & 31;
        const float4* src = (const float4*)(keys_f32 + ((size_t)(b0 + b) * T_ + (t0 + tp)) * H_);
        float4 v = src[c];
        f16* dst = &xlds[(tp * 4 + b) * H_ + c * 4];
        dst[0] = (f16)v.x; dst[1] = (f16)v.y; dst[2] = (f16)v.z; dst[3] = (f16)v.w;
      }
    }
    __syncthreads();
    for (int ngrp = 0; ngrp < 3; ++ngrp) {
      float acc[8][8];
#pragma unroll
      for (int a = 0; a < 8; ++a)
#pragma unroll
        for (int c = 0; c < 8; ++c) acc[a][c] = 0.f;
      for (int kc = 0; kc < 16; ++kc) {
        const int kcp = (kc + n0) & 15;
        H8U xr[8], wr[8];
#pragma unroll
        for (int mi = 0; mi < 8; ++mi)
          xr[mi].v = *(const h8*)&xlds[(mg * 8 + mi) * H_ + kcp * 8];
#pragma unroll
        for (int ni = 0; ni < 8; ++ni)
          wr[ni].v = *(const h8*)&wlds[(n0 * 24 + ngrp * 8 + ni) * H_ + kcp * 8];
#pragma unroll
        for (int mi = 0; mi < 8; ++mi)
#pragma unroll
          for (int ni = 0; ni < 8; ++ni)
#pragma unroll
            for (int q = 0; q < 4; ++q)
              acc[mi][ni] = dot2a(xr[mi].p[q], wr[ni].p[q], acc[mi][ni]);
      }
#pragma unroll
      for (int mi = 0; mi < 8; ++mi) {
        const int pr = mg * 8 + mi;
        if (pr < S * 4) {
          H8U o8;
#pragma unroll
          for (int ni = 0; ni < 8; ++ni) {
            const int g = n0 * 24 + ngrp * 8 + ni;
            o8.p[ni >> 1][ni & 1] = (f16)(acc[mi][ni] + bihs[g]);
          }
          *(h8*)&gi_ws[(size_t)pr * G3_ + n0 * 24 + ngrp * 8] = o8.v;
        }
      }
    }
    __syncthreads();
    for (int tp = 0; tp < S; ++tp) {
      const int t = t0 + tp;
      float hr[2] = {0.f, 0.f}, hz[2] = {0.f, 0.f}, hn[2] = {0.f, 0.f};
#pragma unroll
      for (int kc = 0; kc < 16; ++kc) {
        H8U hv0, hv1;
        hv0.v = *(const h8*)&hbuf[p][(bp)     * H_ + kc * 8];
        hv1.v = *(const h8*)&hbuf[p][(bp + 2) * H_ + kc * 8];
#pragma unroll
        for (int q = 0; q < 4; ++q) {
          hr[0] = dot2a(wr_r[kc].p[q], hv0.p[q], hr[0]);
          hz[0] = dot2a(wr_z[kc].p[q], hv0.p[q], hz[0]);
          hn[0] = dot2a(wr_n[kc].p[q], hv0.p[q], hn[0]);
          hr[1] = dot2a(wr_r[kc].p[q], hv1.p[q], hr[1]);
          hz[1] = dot2a(wr_z[kc].p[q], hv1.p[q], hz[1]);
          hn[1] = dot2a(wr_n[kc].p[q], hv1.p[q], hn[1]);
        }
      }
#pragma unroll
      for (int bb = 0; bb < 2; ++bb) {
        const int b = bp + bb * 2;
        const int gb = b0 + b;
        const f16* gi = &gi_ws[(size_t)(tp * 4 + b) * G3_];
        const float gr  = (float)gi[j]       + hr[bb] + bhr;
        const float gz  = (float)gi[j + 128] + hz[bb] + bhz;
        const float gin = (float)gi[j + 256];
        const float r = sig_(gr);
        const float nn = tanh_(gin + r * (hn[bb] + bhn));
        float hnew;
        if (AUGRU) {
          const float a = scores[(size_t)gb * T_ + t];
          const float u = sig_(gz) * a;
          hnew = (1.f - u) * hreg[bb] + u * nn;
        } else {
          const float z = sig_(gz);
          hnew = (1.f - z) * nn + z * hreg[bb];
        }
        const int mylen = bb ? len1 : len0;
        if (t < mylen) hreg[bb] = hnew;
        hbuf[p ^ 1][b * H_ + j] = (f16)hreg[bb];
        if (!AUGRU) interests_out[((size_t)gb * T_ + t) * H_ + j] = (f16)hreg[bb];
      }
      __syncthreads();
      p ^= 1;
    }
  }
  if (AUGRU) {
    hout[(size_t)(b0 + bp) * H_ + j]     = hreg[0];
    hout[(size_t)(b0 + bp + 2) * H_ + j] = hreg[1];
  }
}

// ---------------------------------------------------------------- attention (MFMA, softmax fused)
__global__ __launch_bounds__(512, 1) void attn_kernel(
    const float* __restrict__ query,
    const f16* __restrict__ interests,
    const f16* __restrict__ wf1g,
    const f16* __restrict__ wf2g,
    const f16* __restrict__ wfg,
    const float* __restrict__ qdotp,
    const float* __restrict__ b2,
    const float* __restrict__ bfp,
    const int* __restrict__ lens,
    float* __restrict__ scores)
{
  __shared__ alignas(16) f16 wf1[NT1 * 8 * 64 * 8];
  __shared__ alignas(16) f16 wf2[NT2 * KS2N * 64 * 8];
  __shared__ alignas(16) f16 uni[29952];
  __shared__ alignas(16) f16 qh[128];
  __shared__ alignas(16) f16 wfv[40];
  __shared__ float qd[80];
  __shared__ float b2s[40];
  __shared__ float red[256];

  f16* ktf = uni;
  f16* h1f = uni;
  f16* h2s = uni + MT1 * KS2N * 64 * 8;

  const int tid = threadIdx.x;
  const int b = blockIdx.x;
  const int lane = tid & 63, wid = tid >> 6;
  const int row = lane & 15, kb = lane >> 4;

  for (int idx = tid; idx < NT1 * 8 * 64; idx += 512)
    ((uint4*)wf1)[idx] = ((const uint4*)wf1g)[idx];
  for (int idx = tid; idx < NT2 * KS2N * 64; idx += 512)
    ((uint4*)wf2)[idx] = ((const uint4*)wf2g)[idx];
  for (int idx = tid; idx < MT1 * 4 * 64; idx += 512) {
    const int l = idx & 63, ks = (idx >> 6) & 3, mt = idx >> 8;
    const int t = mt * 16 + (l & 15);
    uint4 v = make_uint4(0u, 0u, 0u, 0u);
    if (t < T_)
      v = *(const uint4*)(interests + ((size_t)b * T_ + t) * H_ + ks * 32 + ((l >> 4) << 3));
    ((uint4*)ktf)[idx] = v;
  }
  if (tid < 32) {
    float4 qv = ((const float4*)(query + (size_t)b * H_))[tid];
    f16* d = &qh[tid * 4];
    d[0] = (f16)qv.x; d[1] = (f16)qv.y; d[2] = (f16)qv.z; d[3] = (f16)qv.w;
  }
  if (tid < 80) qd[tid] = qdotp[(size_t)b * 80 + tid];
  if (tid >= 128 && tid < 168) wfv[tid - 128] = wfg[tid - 128];
  if (tid >= 192 && tid < 232) b2s[tid - 192] = b2[tid - 192];
  __syncthreads();

  const int nmt = (wid + 8 < MT1) ? 2 : 1;
  const int mts[2] = { wid, wid + 8 };

  h8 qf[4];
#pragma unroll
  for (int h = 0; h < 4; ++h) qf[h] = *(const h8*)&qh[h * 32 + kb * 8];

  h8 afr[2][4], qa[2][4];
#pragma unroll
  for (int m = 0; m < 2; ++m) if (m < nmt) {
#pragma unroll
    for (int ks = 0; ks < 4; ++ks) {
      afr[m][ks] = *(const h8*)&ktf[((mts[m] * 4 + ks) * 64 + lane) * 8];
      qa[m][ks] = afr[m][ks] * qf[ks];
    }
  }
  __syncthreads();

  f32x4 acc[2][NT1];
#pragma unroll
  for (int m = 0; m < 2; ++m)
#pragma unroll
    for (int n = 0; n < NT1; ++n) acc[m][n] = (f32x4){0.f, 0.f, 0.f, 0.f};

  for (int nt = 0; nt < NT1; ++nt) {
#pragma unroll
    for (int ks = 0; ks < 8; ++ks) {
      const h8 bfr = *(const h8*)&wf1[((nt * 8 + ks) * 64 + lane) * 8];
#pragma unroll
      for (int m = 0; m < 2; ++m) if (m < nmt)
        acc[m][nt] = mfma_h(ks < 4 ? afr[m][ks] : qa[m][ks - 4], bfr, acc[m][nt]);
    }
  }

#pragma unroll
  for (int m = 0; m < 2; ++m) if (m < nmt) {
    const int mt = mts[m];
#pragma unroll
    for (int nt = 0; nt < NT1; ++nt) {
      const int o = nt * 16 + row;
      const float qdo = qd[o];
#pragma unroll
      for (int r = 0; r < 4; ++r) {
        const float val = sig_(acc[m][nt][r] + qdo);
        const int lr = kb * 4 + r;
        const int ks2 = o >> 5, kb2 = (o >> 3) & 3, i2 = o & 7;
        h1f[((mt * KS2N + ks2) * 64 + (lr | (kb2 << 4))) * 8 + i2] = (f16)val;
      }
    }
  }
  for (int idx = tid; idx < MT1 * 32 * 8; idx += 512) {
    const int mt = idx >> 8, rr = idx & 255;
    h1f[((mt * KS2N + 2) * 64 + 32 + (rr >> 3)) * 8 + (rr & 7)] = (f16)0.f;
  }
  __syncthreads();

  h8 a2[2][KS2N];
#pragma unroll
  for (int m = 0; m < 2; ++m) if (m < nmt)
#pragma unroll
    for (int ks = 0; ks < KS2N; ++ks)
      a2[m][ks] = *(const h8*)&h1f[((mts[m] * KS2N + ks) * 64 + lane) * 8];

  f32x4 acc2[2][NT2];
#pragma unroll
  for (int m = 0; m < 2; ++m)
#pragma unroll
    for (int n = 0; n < NT2; ++n) acc2[m][n] = (f32x4){0.f, 0.f, 0.f, 0.f};

#pragma unroll
  for (int nt = 0; nt < NT2; ++nt)
#pragma unroll
    for (int ks = 0; ks < KS2N; ++ks) {
      const h8 bfr = *(const h8*)&wf2[((nt * KS2N + ks) * 64 + lane) * 8];
#pragma unroll
      for (int m = 0; m < 2; ++m) if (m < nmt)
        acc2[m][nt] = mfma_h(a2[m][ks], bfr, acc2[m][nt]);
    }

#pragma unroll
  for (int m = 0; m < 2; ++m) if (m < nmt) {
#pragma unroll
    for (int nt = 0; nt < NT2; ++nt) {
      const int o2 = nt * 16 + row;
      if (o2 < 40) {
        const float bo = b2s[o2];
#pragma unroll
        for (int r = 0; r < 4; ++r) {
          const int t = mts[m] * 16 + kb * 4 + r;
          h2s[t * 48 + o2] = (f16)sig_(acc2[m][nt][r] + bo);
        }
      }
    }
  }
  __syncthreads();

  float logit = 0.f;
  if (tid < T_) {
    float a = 0.f;
#pragma unroll
    for (int c = 0; c < 5; ++c) {
      H8U wv, hv;
      wv.v = *(const h8*)&wfv[c * 8];
      hv.v = *(const h8*)&h2s[tid * 48 + c * 8];
#pragma unroll
      for (int q = 0; q < 4; ++q) a = dot2a(wv.p[q], hv.p[q], a);
    }
    logit = (a + bfp[0]) * 0.088388347648318447f;
  }
  const int len = lens[b];
  if (tid < 256) red[tid] = (tid < T_ && tid < len) ? logit : -1e30f;
  __syncthreads();
  for (int s = 128; s > 0; s >>= 1) {
    if (tid < s) red[tid] = fmaxf(red[tid], red[tid + s]);
    __syncthreads();
  }
  const float mx = red[0];
  __syncthreads();
  const float e = (tid < T_ && tid < len) ? __expf(logit - mx) : 0.f;
  if (tid < 256) red[tid] = e;
  __syncthreads();
  for (int s = 128; s > 0; s >>= 1) {
    if (tid < s) red[tid] += red[tid + s];
    __syncthreads();
  }
  if (tid < T_) scores[(size_t)b * T_ + tid] = e * (1.f / red[0]);
}

// ---------------------------------------------------------------- launcher
extern "C" void kernel_launch(void* const* d_in, const int* in_sizes, int n_in,
                              void* d_out, int out_size, void* d_ws, size_t ws_size,
                              hipStream_t stream)
{
  (void)in_sizes; (void)n_in; (void)out_size;
  const float* query = (const float*)d_in[0];
  const float* keys  = (const float*)d_in[1];
  const int*   lens  = (const int*)d_in[2];
  const float* Wih_e = (const float*)d_in[3];
  const float* Whh_e = (const float*)d_in[4];
  const float* bih_e = (const float*)d_in[5];
  const float* bhh_e = (const float*)d_in[6];
  const float* Wih_a = (const float*)d_in[7];
  const float* Whh_a = (const float*)d_in[8];
  const float* bih_a = (const float*)d_in[9];
  const float* bhh_a = (const float*)d_in[10];
  const float* W1 = (const float*)d_in[11];
  const float* b1 = (const float*)d_in[12];
  const float* W2 = (const float*)d_in[13];
  const float* b2 = (const float*)d_in[14];
  const float* Wf = (const float*)d_in[15];
  const float* bf = (const float*)d_in[16];

  char* w = (char*)d_ws;
  size_t off = 0;
  auto take = [&](size_t bytes) { char* p = w + off; off += (bytes + 255) & ~(size_t)255; return p; };

  f16*   interests = (f16*)take((size_t)B_ * T_ * H_ * 2);
  float* scores    = (float*)take((size_t)B_ * T_ * 4);
  f16*   wih_e_h = (f16*)take(G3_ * H_ * 2);
  f16*   whh_e_h = (f16*)take(G3_ * H_ * 2);
  f16*   wih_a_h = (f16*)take(G3_ * H_ * 2);
  f16*   whh_a_h = (f16*)take(G3_ * H_ * 2);
  float* A1f = (float*)take(80 * 128 * 4);
  f16*   Wfh = (f16*)take(64 * 2);
  f16*   wf1p = (f16*)take(NT1 * 8 * 64 * 8 * 2);
  f16*   wf2p = (f16*)take(NT2 * KS2N * 64 * 8 * 2);
  f16*   whhf_e = (f16*)take(WHHF_ELEMS * 2);
  f16*   whhf_a = (f16*)take(WHHF_ELEMS * 2);
  f16*   wihf_e = (f16*)take(WHHF_ELEMS * 2);
  f16*   wihf_a = (f16*)take(WHHF_ELEMS * 2);
  float* qdotp = (float*)take((size_t)B_ * 80 * 4);

  const size_t small_off = off;
  f16* gi_big = (f16*)take((size_t)B_ * T_ * G3_ * 2);
  const size_t need_big = off;
  const bool big = (ws_size >= need_big);
  off = small_off;
  f16* gi_ws = (f16*)take((size_t)SCAN_BLOCKS * CH_ * 4 * G3_ * 2);

  const int prep_tasks = 4 * G3_ * H_ + 80 * 128 + 40
                       + NT1 * 8 * 64 * 8 + NT2 * KS2N * 64 * 8
                       + 4 * WHHF_ELEMS;
  prep_kernel<<<(prep_tasks + 255) / 256, 256, 0, stream>>>(
      Wih_e, Whh_e, Wih_a, Whh_a, W1, W2, Wf,
      wih_e_h, whh_e_h, wih_a_h, whh_a_h, A1f, Wfh, wf1p, wf2p,
      whhf_e, whhf_a, wihf_e, wihf_a);
  qdot_kernel<<<B_, 128, 0, stream>>>(query, A1f, b1, qdotp);

  if (big) {
    gi_gemm_mfma_kernel<1><<<B_ * T_ / 128, 512, 0, stream>>>(
        keys, (const f16*)nullptr, wihf_e, bih_e, gi_big);
    srec_mfma_kernel<0><<<B_ / 16, 512, 0, stream>>>(
        gi_big, lens, whhf_e, bhh_e, (const float*)nullptr, interests, (float*)nullptr);
    attn_kernel<<<B_, 512, 0, stream>>>(
        query, interests, wf1p, wf2p, Wfh, qdotp, b2, bf, lens, scores);
    gi_gemm_mfma_kernel<0><<<B_ * T_ / 128, 512, 0, stream>>>(
        (const float*)nullptr, interests, wihf_a, bih_a, gi_big);
    srec_mfma_kernel<1><<<B_ / 16, 512, 0, stream>>>(
        gi_big, lens, whhf_a, bhh_a, scores, (f16*)nullptr, (float*)d_out);
  } else {
    scan_kernel<0><<<SCAN_BLOCKS, 256, 0, stream>>>(
        keys, (const f16*)nullptr, lens, wih_e_h, whh_e_h, bih_e, bhh_e,
        (const float*)nullptr, interests, (float*)nullptr, gi_ws);
    attn_kernel<<<B_, 512, 0, stream>>>(
        query, interests, wf1p, wf2p, Wfh, qdotp, b2, bf, lens, scores);
    scan_kernel<1><<<SCAN_BLOCKS, 256, 0, stream>>>(
        (const float*)nullptr, interests, lens, wih_a_h, whh_a_h, bih_a, bhh_a,
        scores, (f16*)nullptr, (float*)d_out, gi_ws);
  }
}